// Round 20
// baseline (285.168 us; speedup 1.0000x reference)
//
#include <hip/hip_runtime.h>

#define NNODES 8192
#define NEDGE  262144
#define EETOT  270336     // NEDGE + NNODES (self loops appended)
#define NPAIRS 10000

typedef __attribute__((ext_vector_type(8))) short s16x8;
typedef __attribute__((ext_vector_type(8))) unsigned short u16x8;
typedef __attribute__((ext_vector_type(4))) float f32x4;

__device__ __forceinline__ float lrelu(float v) { return v > 0.f ? v : 0.2f * v; }

// split f32 -> bf16 hi (truncation, exact bits) + bf16 lo (RNE of residual)
__device__ __forceinline__ void split2(float a, unsigned short& h, unsigned short& l) {
  unsigned u = __float_as_uint(a);
  h = (unsigned short)(u >> 16);
  float hf = __uint_as_float(u & 0xffff0000u);
  float r = a - hf;
  unsigned v = __float_as_uint(r);
  v += 0x7fffu + ((v >> 16) & 1u);
  l = (unsigned short)(v >> 16);
}

__device__ __forceinline__ unsigned short f2bf(float f) {   // RNE
  unsigned u = __float_as_uint(f);
  u += 0x7fffu + ((u >> 16) & 1u);
  return (unsigned short)(u >> 16);
}
__device__ __forceinline__ float bf2f(unsigned short u) {
  return __uint_as_float((unsigned)u << 16);
}

// ---- attn row fill: zero 32KB row (NT) + set edge positions; needs src-CSR only ----
__device__ __forceinline__ void attn_fill_row(int row, const int* __restrict__ csrdst,
    const int* __restrict__ rowst_s, float* __restrict__ attn) {
  float* rp = attn + (size_t)row * NNODES;
  f32x4* p4 = (f32x4*)rp;
  f32x4 z = {0.f, 0.f, 0.f, 0.f};
#pragma unroll
  for (int j = 0; j < 8; ++j)
    __builtin_nontemporal_store(z, p4 + j * 256 + threadIdx.x);
  __syncthreads();
  int e0 = rowst_s[row], e1 = rowst_s[row + 1];
  for (int j = e0 + (int)threadIdx.x; j < e1; j += 256)
    rp[csrdst[j]] = 16384.0f / 270336.0f;
}

// ---------------- merged weight pre-transpose (RNE bf16) + zero-init ----------------
__device__ __forceinline__ void wsplit_body(const float* __restrict__ W,
    unsigned short* __restrict__ Th, int K, int blk) {
  int col = threadIdx.x;
  int kb = blk * 8;
  u16x8 vh;
#pragma unroll
  for (int i = 0; i < 8; ++i)
    vh[i] = f2bf(W[(size_t)(kb + i) * 256 + col]);
  *(u16x8*)(Th + (size_t)col * K + kb) = vh;
}

__global__ __launch_bounds__(256) void k_wsplit_all(
    const float* __restrict__ Wd, const float* __restrict__ Wc, const float* __restrict__ Wg,
    const float* __restrict__ W1l, const float* __restrict__ W1r,
    const float* __restrict__ W2l, const float* __restrict__ W2r,
    unsigned short* __restrict__ tdh, unsigned short* __restrict__ tch,
    unsigned short* __restrict__ tgh,
    unsigned short* __restrict__ tl1h, unsigned short* __restrict__ tr1h,
    unsigned short* __restrict__ tl2h, unsigned short* __restrict__ tr2h,
    int* __restrict__ counts_d, int* __restrict__ counts_s, float* __restrict__ stats) {
  int b = blockIdx.x;
  if      (b < 256)  wsplit_body(Wd,  tdh, 2048, b);
  else if (b < 512)  wsplit_body(Wc,  tch, 2048, b - 256);
  else if (b < 1024) wsplit_body(Wg,  tgh, 4096, b - 512);
  else if (b < 1056) { wsplit_body(W1l, tl1h, 256, b - 1024);
                       counts_d[(b - 1024) * 256 + threadIdx.x] = 0; }
  else if (b < 1088) { wsplit_body(W1r, tr1h, 256, b - 1056);
                       counts_s[(b - 1056) * 256 + threadIdx.x] = 0; }
  else if (b < 1120) { wsplit_body(W2l, tl2h, 256, b - 1088);
                       if (b < 1092) stats[(b - 1088) * 256 + threadIdx.x] = 0.f; }
  else               wsplit_body(W2r, tr2h, 256, b - 1120);
}

// ---------------- 128x128 MFMA 2-term bf16 GEMM tile, 2-deep reg pipeline ----------
struct Tile128 {
  unsigned short Ah[128][40], Al[128][40], Bh[128][40];   // +8 pad: bank spread
};
struct TileN {       // NORM variant carries per-channel scale/shift in LDS
  Tile128 t;
  float nsc[256], nsh[256];
};

template<bool BIAS, bool OUTBF, bool NORM>
__device__ __forceinline__ void gemm_tile128(Tile128& s,
    const float* __restrict__ A, int lda,
    const unsigned short* __restrict__ Th, int ldb, int nsteps,
    const float* __restrict__ bias, float* __restrict__ C,
    unsigned short* __restrict__ Cb,
    const float* __restrict__ nsc, const float* __restrict__ nsh) {
  const int tid = threadIdx.x;
  const int wave = tid >> 6, lane = tid & 63;
  const int g = lane >> 4, r = lane & 15;
  const int wr = (wave >> 1) * 64, wc = (wave & 1) * 64;

  const int ar = tid >> 1, ak = (tid & 1) * 16;      // A: 128 rows x 32 k
  const float* Arow = A + (size_t)ar * lda + ak;
  const int bc = tid & 127, bk = (tid >> 7) * 16;    // B: 128 cols x 32 k
  const unsigned short* Bhs = Th + (size_t)bc * ldb + bk;

  f32x4 acc[4][4];
#pragma unroll
  for (int m = 0; m < 4; ++m)
#pragma unroll
    for (int n = 0; n < 4; ++n)
#pragma unroll
      for (int j = 0; j < 4; ++j) acc[m][n][j] = 0.f;

  // 2-deep register pipeline: q* = step t (to stage), p* = step t+1 (in flight)
  float4 qa0 = *(const float4*)(Arow);
  float4 qa1 = *(const float4*)(Arow + 4);
  float4 qa2 = *(const float4*)(Arow + 8);
  float4 qa3 = *(const float4*)(Arow + 12);
  u16x8 qb0 = *(const u16x8*)(Bhs);
  u16x8 qb1 = *(const u16x8*)(Bhs + 8);
  float4 pa0, pa1, pa2, pa3;
  u16x8 pb0, pb1;
  if (nsteps > 1) {
    pa0 = *(const float4*)(Arow + 32);
    pa1 = *(const float4*)(Arow + 36);
    pa2 = *(const float4*)(Arow + 40);
    pa3 = *(const float4*)(Arow + 44);
    pb0 = *(const u16x8*)(Bhs + 32);
    pb1 = *(const u16x8*)(Bhs + 40);
  }

  for (int t = 0; t < nsteps; ++t) {
    {
      float av[16] = {qa0.x, qa0.y, qa0.z, qa0.w, qa1.x, qa1.y, qa1.z, qa1.w,
                      qa2.x, qa2.y, qa2.z, qa2.w, qa3.x, qa3.y, qa3.z, qa3.w};
      u16x8 vh0, vh1, vl0, vl1;
#pragma unroll
      for (int i = 0; i < 16; ++i) {
        float v = av[i];
        if constexpr (NORM) {
          int ch = t * 32 + ak + i;
          v = fmaxf(v * nsc[ch] + nsh[ch], 0.f);
        }
        unsigned short hh, ll;
        split2(v, hh, ll);
        if (i < 8) { vh0[i] = hh; vl0[i] = ll; }
        else       { vh1[i - 8] = hh; vl1[i - 8] = ll; }
      }
      *(u16x8*)&s.Ah[ar][ak]     = vh0;
      *(u16x8*)&s.Ah[ar][ak + 8] = vh1;
      *(u16x8*)&s.Al[ar][ak]     = vl0;
      *(u16x8*)&s.Al[ar][ak + 8] = vl1;
      *(u16x8*)&s.Bh[bc][bk]     = qb0;
      *(u16x8*)&s.Bh[bc][bk + 8] = qb1;
    }
    __syncthreads();
    // rotate pipeline and issue step t+2's loads (2 compute-phases of cover)
    qa0 = pa0; qa1 = pa1; qa2 = pa2; qa3 = pa3;
    qb0 = pb0; qb1 = pb1;
    if (t + 2 < nsteps) {
      const float* An = Arow + (size_t)(t + 2) * 32;
      pa0 = *(const float4*)(An);
      pa1 = *(const float4*)(An + 4);
      pa2 = *(const float4*)(An + 8);
      pa3 = *(const float4*)(An + 12);
      const unsigned short* Bhn = Bhs + (size_t)(t + 2) * 32;
      pb0 = *(const u16x8*)(Bhn);
      pb1 = *(const u16x8*)(Bhn + 8);
    }
    s16x8 fah[4], fal[4], fbh[4];
#pragma unroll
    for (int m = 0; m < 4; ++m) {
      fah[m] = *(const s16x8*)&s.Ah[wr + m * 16 + r][g * 8];
      fal[m] = *(const s16x8*)&s.Al[wr + m * 16 + r][g * 8];
    }
#pragma unroll
    for (int n = 0; n < 4; ++n)
      fbh[n] = *(const s16x8*)&s.Bh[wc + n * 16 + r][g * 8];
#pragma unroll
    for (int m = 0; m < 4; ++m)
#pragma unroll
      for (int n = 0; n < 4; ++n) {
        acc[m][n] = __builtin_amdgcn_mfma_f32_16x16x32_bf16(fal[m], fbh[n], acc[m][n], 0, 0, 0);
        acc[m][n] = __builtin_amdgcn_mfma_f32_16x16x32_bf16(fah[m], fbh[n], acc[m][n], 0, 0, 0);
      }
    __syncthreads();
  }
  // epilogue: C/D layout col=lane&15, row=(lane>>4)*4+reg [m89]
#pragma unroll
  for (int m = 0; m < 4; ++m)
#pragma unroll
    for (int n = 0; n < 4; ++n) {
      int col = wc + n * 16 + r;
      float bv = BIAS ? bias[col] : 0.f;
      int rowb = wr + m * 16 + g * 4;
#pragma unroll
      for (int j = 0; j < 4; ++j) {
        float v = acc[m][n][j] + bv;
        if constexpr (OUTBF) Cb[(size_t)(rowb + j) * 256 + col] = f2bf(v);
        else                 C[(size_t)(rowb + j) * 256 + col] = v;
      }
    }
}

// ---- merged: split-K input projections (blocks 0..511) + attn fill rows 0..2047 ----
#define PDRUG_PLANE ((size_t)2048 * 256)
#define PGENE_PLANE ((size_t)4096 * 256)
__global__ __launch_bounds__(256) void k_inproj_fill(
    const float* __restrict__ drug, const float* __restrict__ cell,
    const float* __restrict__ gene,
    const unsigned short* __restrict__ tdh, const unsigned short* __restrict__ tch,
    const unsigned short* __restrict__ tgh, float* __restrict__ P,
    const int* __restrict__ csrdst, const int* __restrict__ rowst_s,
    float* __restrict__ attn) {
  __shared__ Tile128 s;
  int b = blockIdx.x;
  if (b >= 512) { attn_fill_row(b - 512, csrdst, rowst_s, attn); return; }
  if (b < 256) {          // drug (b<128) / cell: 16 rowblk x 2 colblk x 4 kchunk (K=512)
    int idx = b & 127;
    int colblk = (idx >> 3) & 1;
    int rest = (idx & 7) | ((idx >> 4) << 3);   // 0..63
    int rowblk = rest >> 2, chunk = rest & 3;
    const float* X = (b < 128) ? drug : cell;
    const unsigned short* Th = (b < 128) ? tdh : tch;
    float* Pb = P + ((b < 128) ? 0 : 4 * PDRUG_PLANE);
    gemm_tile128<false, false, false>(s,
        X + (size_t)rowblk * 128 * 2048 + (size_t)chunk * 512, 2048,
        Th + (size_t)colblk * 128 * 2048 + chunk * 512, 2048, 16, nullptr,
        Pb + (size_t)chunk * PDRUG_PLANE + (size_t)rowblk * 128 * 256 + colblk * 128,
        nullptr, nullptr, nullptr);
  } else {                // gene: 32 rowblk x 2 colblk x 4 kchunk (K=1024, 32 steps)
    int idx = b - 256;    // 0..255
    int colblk = (idx >> 3) & 1;
    int rest = (idx & 7) | ((idx >> 4) << 3);   // 0..127
    int rowblk = rest >> 2, chunk = rest & 3;
    gemm_tile128<false, false, false>(s,
        gene + (size_t)rowblk * 128 * 4096 + (size_t)chunk * 1024, 4096,
        tgh + (size_t)colblk * 128 * 4096 + chunk * 1024, 4096, 32, nullptr,
        P + 8 * PDRUG_PLANE + (size_t)chunk * PGENE_PLANE + (size_t)rowblk * 128 * 256 + colblk * 128,
        nullptr, nullptr, nullptr);
  }
}

// reduce partial planes (np=4 uniform) + bias -> bufA [8192, 256]
__global__ __launch_bounds__(256) void k_reduce(const float* __restrict__ P,
    const float* __restrict__ bd, const float* __restrict__ bc,
    const float* __restrict__ bg, float* __restrict__ out) {
  int idx = blockIdx.x * 256 + threadIdx.x;   // float4 index
  size_t e = (size_t)idx * 4;
  int row = (int)(e >> 8);
  int col = (int)(e & 255);
  const float* base; const float* bias; size_t plane;
  if (row < 2048) {
    base = P + (size_t)row * 256 + col; bias = bd; plane = PDRUG_PLANE;
  } else if (row < 4096) {
    base = P + 4 * PDRUG_PLANE + (size_t)(row - 2048) * 256 + col; bias = bc;
    plane = PDRUG_PLANE;
  } else {
    base = P + 8 * PDRUG_PLANE + (size_t)(row - 4096) * 256 + col; bias = bg;
    plane = PGENE_PLANE;
  }
  float4 s = *(const float4*)(base);
#pragma unroll
  for (int p = 1; p < 4; ++p) {
    float4 v = *(const float4*)(base + p * plane);
    s.x += v.x; s.y += v.y; s.z += v.z; s.w += v.w;
  }
  float4 bv = *(const float4*)(bias + col);
  s.x += bv.x; s.y += bv.y; s.z += bv.z; s.w += bv.w;
  *(float4*)(out + e) = s;
}

// merged layer GEMMs (blocks 0..255) + attn fill backfill (blocks 256..1279).
template<bool NORM>
__global__ __launch_bounds__(256) void k_gemm2(const float* __restrict__ A,
    const unsigned short* __restrict__ ThL, const unsigned short* __restrict__ ThR,
    const float* __restrict__ biasL, const float* __restrict__ biasR,
    unsigned short* __restrict__ CLb, unsigned short* __restrict__ CRb,
    const float* __restrict__ csum, const float* __restrict__ csumsq,
    const float* __restrict__ gamma, const float* __restrict__ beta,
    const float* __restrict__ mscale,
    const int* __restrict__ csrdst, const int* __restrict__ rowst_s,
    float* __restrict__ attn, int fill_base) {
  __shared__ TileN s;
  int b = blockIdx.x;
  if (b >= 256) { attn_fill_row(fill_base + b - 256, csrdst, rowst_s, attn); return; }
  int sub = (b >> 3) & 3;
  int x = (b & 7) | ((b >> 5) << 3);     // 0..63
  if constexpr (NORM) {
    int c = threadIdx.x;
    float mu = csum[c] * (1.0f / 8192.0f);
    float ex2 = csumsq[c] * (1.0f / 8192.0f);
    float smu = mscale[c] * mu;
    float var = ex2 - 2.f * smu * mu + smu * smu;
    float sc = rsqrtf(var + 1e-5f) * gamma[c];
    s.nsc[c] = sc;
    s.nsh[c] = beta[c] - smu * sc;
    __syncthreads();
  }
  int row0 = x * 128;
  int col0 = (sub & 1) * 128;
  if (sub >= 2) {
    gemm_tile128<true, true, NORM>(s.t, A + (size_t)row0 * 256, 256,
        ThR + (size_t)col0 * 256, 256, 8,
        biasR + col0, nullptr, CRb + (size_t)row0 * 256 + col0, s.nsc, s.nsh);
  } else {
    gemm_tile128<true, true, NORM>(s.t, A + (size_t)row0 * 256, 256,
        ThL + (size_t)col0 * 256, 256, 8,
        biasL + col0, nullptr, CLb + (size_t)row0 * 256 + col0, s.nsc, s.nsh);
  }
}

// ---------------- dual CSR build (counting sort by dst AND by src) ----------------
__global__ void k_count2(const int* __restrict__ edges, int* __restrict__ cd,
                         int* __restrict__ cs) {
  int e = blockIdx.x * blockDim.x + threadIdx.x;
  if (e >= EETOT) return;
  int s, d;
  if (e < NEDGE) { s = edges[e]; d = edges[NEDGE + e]; } else { s = d = e - NEDGE; }
  atomicAdd(&cd[d], 1);
  atomicAdd(&cs[s], 1);
}

__global__ __launch_bounds__(1024) void k_scan2(
    const int* __restrict__ c0, int* __restrict__ r0, int* __restrict__ u0,
    const int* __restrict__ c1, int* __restrict__ r1, int* __restrict__ u1) {
  const int* counts = blockIdx.x ? c1 : c0;
  int* row_start = blockIdx.x ? r1 : r0;
  int* cursor = blockIdx.x ? u1 : u0;
  __shared__ int part[1024];
  int t = threadIdx.x;
  int base = t * 8;
  int loc[8];
  int s = 0;
#pragma unroll
  for (int j = 0; j < 8; ++j) { loc[j] = s; s += counts[base + j]; }
  part[t] = s;
  __syncthreads();
  for (int off = 1; off < 1024; off <<= 1) {
    int v = (t >= off) ? part[t - off] : 0;
    __syncthreads();
    part[t] += v;
    __syncthreads();
  }
  int pre = (t == 0) ? 0 : part[t - 1];
#pragma unroll
  for (int j = 0; j < 8; ++j) {
    int v = pre + loc[j];
    row_start[base + j] = v;
    cursor[base + j] = v;
  }
  if (t == 1023) row_start[NNODES] = pre + s;
}

__global__ void k_place2(const int* __restrict__ edges, int* __restrict__ curd,
    int* __restrict__ curs, int* __restrict__ csrsrc, int* __restrict__ csrdst) {
  int e = blockIdx.x * blockDim.x + threadIdx.x;
  if (e >= EETOT) return;
  int s, d;
  if (e < NEDGE) { s = edges[e]; d = edges[NEDGE + e]; } else { s = d = e - NEDGE; }
  int pd = atomicAdd(&curd[d], 1);
  csrsrc[pd] = s;                       // src ids ordered by dst (for k_gat)
  int ps = atomicAdd(&curs[s], 1);
  csrdst[ps] = d;                       // dst ids ordered by src (for attnfill)
}

// ---- fused GAT edge phase (blocks 0..2047) + attn fill backfill (2048..4095) ----
__global__ __launch_bounds__(256) void k_gat(
    const unsigned short* __restrict__ xl, const unsigned short* __restrict__ xr,
    const float* __restrict__ att, const int* __restrict__ csrsrc,
    const int* __restrict__ row_start, const float* __restrict__ bias,
    float* __restrict__ out,
    const int* __restrict__ csrdst, const int* __restrict__ rowst_s,
    float* __restrict__ attn, int fill_base) {
  if (blockIdx.x >= 2048) {
    attn_fill_row(fill_base + blockIdx.x - 2048, csrdst, rowst_s, attn);
    return;
  }
  int i = blockIdx.x * 4 + (threadIdx.x >> 6);
  int lane = threadIdx.x & 63;
  int co = (lane >> 4) * 64 + (lane & 15) * 4;   // head*64 + channel
  float4 w4 = *(const float4*)(att + co);
  ushort4 ur = *(const ushort4*)(xr + (size_t)i * 256 + co);
  float4 r4;
  r4.x = bf2f(ur.x); r4.y = bf2f(ur.y); r4.z = bf2f(ur.z); r4.w = bf2f(ur.w);
  float sum = 0.f, ax = 0.f, ay = 0.f, az = 0.f, aw = 0.f;
  int e0 = row_start[i], e1 = row_start[i + 1];   // >=1 edge (self loop)
  int deg = e1 - e0;

  for (int cb = 0; cb < deg; cb += 64) {          // chunks of <=64 edges
    int cn = min(deg - cb, 64);                   // wave-uniform
    int myid = (lane < cn) ? csrsrc[e0 + cb + lane] : 0;
    auto g = [&](int j) {
      int s = __shfl(myid, j);
      return *(const ushort4*)(xl + (size_t)s * 256 + co);
    };
    ushort4 cur[8], nxt[8];
    int curn = min(cn, 8);
#pragma unroll
    for (int j = 0; j < 8; ++j)
      if (j < curn) cur[j] = g(j);
    int p = curn;
    for (;;) {
      int nxtn = min(cn - p, 8);                  // wave-uniform
#pragma unroll
      for (int j = 0; j < 8; ++j)
        if (j < nxtn) nxt[j] = g(p + j);
#pragma unroll
      for (int j = 0; j < 8; ++j) {
        if (j >= curn) break;
        ushort4 u = cur[j];
        float x0 = bf2f(u.x), x1 = bf2f(u.y), x2 = bf2f(u.z), x3 = bf2f(u.w);
        float t = w4.x * lrelu(x0 + r4.x) + w4.y * lrelu(x1 + r4.y) +
                  w4.z * lrelu(x2 + r4.z) + w4.w * lrelu(x3 + r4.w);
        t += __shfl_xor(t, 1);
        t += __shfl_xor(t, 2);
        t += __shfl_xor(t, 4);
        t += __shfl_xor(t, 8);
        float el = __expf(fminf(t, 60.f));
        sum += el;
        ax += el * x0; ay += el * x1; az += el * x2; aw += el * x3;
      }
      if (nxtn <= 0) break;
#pragma unroll
      for (int j = 0; j < 8; ++j) cur[j] = nxt[j];
      curn = nxtn; p += nxtn;
    }
  }
  float inv = 1.0f / sum;
  float4 bv = *(const float4*)(bias + co);
  float4 r;
  r.x = ax * inv + bv.x; r.y = ay * inv + bv.y;
  r.z = az * inv + bv.z; r.w = aw * inv + bv.w;
  *(float4*)(out + (size_t)i * 256 + co) = r;
}

// ---------------- GraphNorm stats (col sum / sumsq) ----------------
__global__ __launch_bounds__(256) void k_colstats(const float* __restrict__ x,
    float* __restrict__ csum, float* __restrict__ csumsq) {
  int c = threadIdx.x;
  int r0 = blockIdx.x * 32;
  float s = 0.f, s2 = 0.f;
  for (int r = 0; r < 32; ++r) {
    float v = x[(size_t)(r0 + r) * 256 + c];
    s += v; s2 += v * v;
  }
  atomicAdd(&csum[c], s);
  atomicAdd(&csumsq[c], s2);
}

// ---------------- pair head with fused GraphNorm+ReLU of the final features -------
__global__ __launch_bounds__(256) void k_pred(const float* __restrict__ h,
    const int* __restrict__ idx_drug, const int* __restrict__ idx_cell,
    const float* __restrict__ W, const float* __restrict__ b,
    const float* __restrict__ csum, const float* __restrict__ csumsq,
    const float* __restrict__ gamma, const float* __restrict__ beta,
    const float* __restrict__ mscale, float* __restrict__ out) {
  int p = blockIdx.x * 4 + (threadIdx.x >> 6);
  if (p >= NPAIRS) return;
  int lane = threadIdx.x & 63;
  int rd = idx_drug[p], rc = idx_cell[p];
  float4 a  = *(const float4*)(h + (size_t)rd * 256 + lane * 4);
  float4 cg = *(const float4*)(h + (size_t)rc * 256 + lane * 4);
  float4 wa = *(const float4*)(W + lane * 4);
  float4 wc = *(const float4*)(W + 256 + lane * 4);
  float av[4] = {a.x, a.y, a.z, a.w};
  float cv[4] = {cg.x, cg.y, cg.z, cg.w};
  float wv[4] = {wa.x, wa.y, wa.z, wa.w};
  float uv[4] = {wc.x, wc.y, wc.z, wc.w};
  float t = 0.f;
#pragma unroll
  for (int j = 0; j < 4; ++j) {
    int ch = lane * 4 + j;
    float mu = csum[ch] * (1.0f / 8192.0f);
    float ex2 = csumsq[ch] * (1.0f / 8192.0f);
    float smu = mscale[ch] * mu;
    float var = ex2 - 2.f * smu * mu + smu * smu;
    float sc = rsqrtf(var + 1e-5f) * gamma[ch];
    float sh = beta[ch] - smu * sc;
    t += fmaxf(av[j] * sc + sh, 0.f) * wv[j] + fmaxf(cv[j] * sc + sh, 0.f) * uv[j];
  }
#pragma unroll
  for (int off = 1; off < 64; off <<= 1) t += __shfl_xor(t, off);
  if (lane == 0) out[p] = 1.0f / (1.0f + __expf(-(t + b[0])));
}

extern "C" void kernel_launch(void* const* d_in, const int* in_sizes, int n_in,
                              void* d_out, int out_size, void* d_ws, size_t ws_size,
                              hipStream_t stream) {
  const float* drug = (const float*)d_in[0];
  const float* cell = (const float*)d_in[1];
  const float* gene = (const float*)d_in[2];
  const int*   edges = (const int*)d_in[3];
  const int*   idxd = (const int*)d_in[4];
  const int*   idxc = (const int*)d_in[5];
  const float* Wd = (const float*)d_in[6];   const float* bd = (const float*)d_in[7];
  const float* Wc = (const float*)d_in[8];   const float* bc = (const float*)d_in[9];
  const float* Wg = (const float*)d_in[10];  const float* bg = (const float*)d_in[11];
  const float* g1Wl = (const float*)d_in[12]; const float* g1bl = (const float*)d_in[13];
  const float* g1Wr = (const float*)d_in[14]; const float* g1br = (const float*)d_in[15];
  const float* g1att = (const float*)d_in[16]; const float* g1bias = (const float*)d_in[17];
  const float* g2Wl = (const float*)d_in[18]; const float* g2bl = (const float*)d_in[19];
  const float* g2Wr = (const float*)d_in[20]; const float* g2br = (const float*)d_in[21];
  const float* g2att = (const float*)d_in[22]; const float* g2bias = (const float*)d_in[23];
  const float* gn1g = (const float*)d_in[24]; const float* gn1b = (const float*)d_in[25];
  const float* gn1s = (const float*)d_in[26];
  const float* gn2g = (const float*)d_in[27]; const float* gn2b = (const float*)d_in[28];
  const float* gn2s = (const float*)d_in[29];
  const float* linW = (const float*)d_in[30]; const float* linb = (const float*)d_in[31];
  float* out = (float*)d_out;
  (void)in_sizes; (void)n_in; (void)out_size; (void)ws_size;

  char* ws = (char*)d_ws;
  size_t off = 0;
  auto take = [&](size_t bytes) -> void* {
    void* p = ws + off;
    off += (bytes + 255) & ~(size_t)255;
    return p;
  };
  float* bufA = (float*)take((size_t)NNODES * 256 * 4);
  unsigned short* bufBb = (unsigned short*)take((size_t)NNODES * 256 * 2);  // xl bf16
  unsigned short* bufCb = (unsigned short*)take((size_t)NNODES * 256 * 2);  // xr bf16
  int* counts_d = (int*)take((size_t)NNODES * 4);
  int* counts_s = (int*)take((size_t)NNODES * 4);
  float* stats  = (float*)take(4 * 256 * 4);     // csum0|csumsq0|csum1|csumsq1
  int* rowst_d  = (int*)take((size_t)(NNODES + 1) * 4);
  int* rowst_s  = (int*)take((size_t)(NNODES + 1) * 4);
  int* cursor_d = (int*)take((size_t)NNODES * 4);
  int* cursor_s = (int*)take((size_t)NNODES * 4);
  int* csrsrc   = (int*)take((size_t)EETOT * 4);
  int* csrdst   = (int*)take((size_t)EETOT * 4);
  unsigned short* tdh = (unsigned short*)take((size_t)256 * 2048 * 2);
  unsigned short* tch = (unsigned short*)take((size_t)256 * 2048 * 2);
  unsigned short* tgh = (unsigned short*)take((size_t)256 * 4096 * 2);
  unsigned short* tl1h = (unsigned short*)take((size_t)256 * 256 * 2);
  unsigned short* tr1h = (unsigned short*)take((size_t)256 * 256 * 2);
  unsigned short* tl2h = (unsigned short*)take((size_t)256 * 256 * 2);
  unsigned short* tr2h = (unsigned short*)take((size_t)256 * 256 * 2);
  float* Ppart = (float*)take((8 * PDRUG_PLANE + 4 * PGENE_PLANE) * 4);
  float* attn = out + NPAIRS;

  // ---- weight transpose (bf16 RNE) + zero-init of counts & stats (one kernel) ----
  k_wsplit_all<<<1152, 256, 0, stream>>>(Wd, Wc, Wg, g1Wl, g1Wr, g2Wl, g2Wr,
      tdh, tch, tgh, tl1h, tr1h, tl2h, tr2h, counts_d, counts_s, stats);

  // ---- dual CSR build ----
  k_count2<<<EETOT / 256, 256, 0, stream>>>(edges, counts_d, counts_s);
  k_scan2<<<2, 1024, 0, stream>>>(counts_d, rowst_d, cursor_d, counts_s, rowst_s, cursor_s);
  k_place2<<<EETOT / 256, 256, 0, stream>>>(edges, cursor_d, cursor_s, csrsrc, csrdst);

  // ---- input projections + attn fill rows 0..2047 ----
  k_inproj_fill<<<512 + 2048, 256, 0, stream>>>(drug, cell, gene, tdh, tch, tgh,
      Ppart, csrdst, rowst_s, attn);
  k_reduce<<<NNODES * 256 / 4 / 256, 256, 0, stream>>>(Ppart, bd, bc, bg, bufA);

  // ---- layer 0 (raw A); fill rows 2048..3071 / 3072..5119 backfilled ----
  k_gemm2<false><<<256 + 1024, 256, 0, stream>>>(bufA, tl1h, tr1h, g1bl, g1br,
      bufBb, bufCb, nullptr, nullptr, nullptr, nullptr, nullptr,
      csrdst, rowst_s, attn, 2048);
  k_gat<<<2048 + 2048, 256, 0, stream>>>(bufBb, bufCb, g1att, csrsrc, rowst_d, g1bias,
      bufA, csrdst, rowst_s, attn, 3072);
  k_colstats<<<NNODES / 32, 256, 0, stream>>>(bufA, stats, stats + 256);

  // ---- layer 1 (GraphNorm+ReLU fused into A-staging); fill rows 5120..8191 ----
  k_gemm2<true><<<256 + 1024, 256, 0, stream>>>(bufA, tl2h, tr2h, g2bl, g2br,
      bufBb, bufCb, stats, stats + 256, gn1g, gn1b, gn1s,
      csrdst, rowst_s, attn, 5120);
  k_gat<<<2048 + 2048, 256, 0, stream>>>(bufBb, bufCb, g2att, csrsrc, rowst_d, g2bias,
      bufA, csrdst, rowst_s, attn, 6144);
  k_colstats<<<NNODES / 32, 256, 0, stream>>>(bufA, stats + 512, stats + 768);

  // ---- pair predictions (final GraphNorm+ReLU fused) -> out[0..9999] ----
  k_pred<<<NPAIRS / 4, 256, 0, stream>>>(bufA, idxd, idxc, linW, linb,
      stats + 512, stats + 768, gn2g, gn2b, gn2s, out);
}

// Round 21
// 281.075 us; speedup vs baseline: 1.0146x; 1.0146x over previous
//
#include <hip/hip_runtime.h>

#define NNODES 8192
#define NEDGE  262144
#define EETOT  270336     // NEDGE + NNODES (self loops appended)
#define NPAIRS 10000

typedef __attribute__((ext_vector_type(8))) short s16x8;
typedef __attribute__((ext_vector_type(8))) unsigned short u16x8;
typedef __attribute__((ext_vector_type(4))) float f32x4;

__device__ __forceinline__ float lrelu(float v) { return v > 0.f ? v : 0.2f * v; }

// split f32 -> bf16 hi (truncation, exact bits) + bf16 lo (RNE of residual)
__device__ __forceinline__ void split2(float a, unsigned short& h, unsigned short& l) {
  unsigned u = __float_as_uint(a);
  h = (unsigned short)(u >> 16);
  float hf = __uint_as_float(u & 0xffff0000u);
  float r = a - hf;
  unsigned v = __float_as_uint(r);
  v += 0x7fffu + ((v >> 16) & 1u);
  l = (unsigned short)(v >> 16);
}

__device__ __forceinline__ unsigned short f2bf(float f) {   // RNE
  unsigned u = __float_as_uint(f);
  u += 0x7fffu + ((u >> 16) & 1u);
  return (unsigned short)(u >> 16);
}
__device__ __forceinline__ float bf2f(unsigned short u) {
  return __uint_as_float((unsigned)u << 16);
}

// ---- attn row fill: zero 32KB row (NT) + set edge positions; needs src-CSR only ----
__device__ __forceinline__ void attn_fill_row(int row, const int* __restrict__ csrdst,
    const int* __restrict__ rowst_s, float* __restrict__ attn) {
  float* rp = attn + (size_t)row * NNODES;
  f32x4* p4 = (f32x4*)rp;
  f32x4 z = {0.f, 0.f, 0.f, 0.f};
#pragma unroll
  for (int j = 0; j < 8; ++j)
    __builtin_nontemporal_store(z, p4 + j * 256 + threadIdx.x);
  __syncthreads();
  int e0 = rowst_s[row], e1 = rowst_s[row + 1];
  for (int j = e0 + (int)threadIdx.x; j < e1; j += 256)
    rp[csrdst[j]] = 16384.0f / 270336.0f;
}

// ---------------- merged weight pre-transpose (RNE bf16) + zero-init ----------------
__device__ __forceinline__ void wsplit_body(const float* __restrict__ W,
    unsigned short* __restrict__ Th, int K, int blk) {
  int col = threadIdx.x;
  int kb = blk * 8;
  u16x8 vh;
#pragma unroll
  for (int i = 0; i < 8; ++i)
    vh[i] = f2bf(W[(size_t)(kb + i) * 256 + col]);
  *(u16x8*)(Th + (size_t)col * K + kb) = vh;
}

__global__ __launch_bounds__(256) void k_wsplit_all(
    const float* __restrict__ Wd, const float* __restrict__ Wc, const float* __restrict__ Wg,
    const float* __restrict__ W1l, const float* __restrict__ W1r,
    const float* __restrict__ W2l, const float* __restrict__ W2r,
    unsigned short* __restrict__ tdh, unsigned short* __restrict__ tch,
    unsigned short* __restrict__ tgh,
    unsigned short* __restrict__ tl1h, unsigned short* __restrict__ tr1h,
    unsigned short* __restrict__ tl2h, unsigned short* __restrict__ tr2h,
    int* __restrict__ counts_d, int* __restrict__ counts_s, float* __restrict__ stats) {
  int b = blockIdx.x;
  if      (b < 256)  wsplit_body(Wd,  tdh, 2048, b);
  else if (b < 512)  wsplit_body(Wc,  tch, 2048, b - 256);
  else if (b < 1024) wsplit_body(Wg,  tgh, 4096, b - 512);
  else if (b < 1056) { wsplit_body(W1l, tl1h, 256, b - 1024);
                       counts_d[(b - 1024) * 256 + threadIdx.x] = 0; }
  else if (b < 1088) { wsplit_body(W1r, tr1h, 256, b - 1056);
                       counts_s[(b - 1056) * 256 + threadIdx.x] = 0; }
  else if (b < 1120) { wsplit_body(W2l, tl2h, 256, b - 1088);
                       if (b < 1092) stats[(b - 1088) * 256 + threadIdx.x] = 0.f; }
  else               wsplit_body(W2r, tr2h, 256, b - 1120);
}

// ---------------- 128x128 MFMA 2-term bf16 GEMM tile, 2-deep reg pipeline ----------
struct Tile128 {
  unsigned short Ah[128][40], Al[128][40], Bh[128][40];   // +8 pad: bank spread
};
struct TileN {       // NORM variant carries per-channel scale/shift in LDS
  Tile128 t;
  float nsc[256], nsh[256];
};

template<bool BIAS, bool OUTBF, bool NORM>
__device__ __forceinline__ void gemm_tile128(Tile128& s,
    const float* __restrict__ A, int lda,
    const unsigned short* __restrict__ Th, int ldb, int nsteps,
    const float* __restrict__ bias, float* __restrict__ C,
    unsigned short* __restrict__ Cb,
    const float* __restrict__ nsc, const float* __restrict__ nsh) {
  const int tid = threadIdx.x;
  const int wave = tid >> 6, lane = tid & 63;
  const int g = lane >> 4, r = lane & 15;
  const int wr = (wave >> 1) * 64, wc = (wave & 1) * 64;

  const int ar = tid >> 1, ak = (tid & 1) * 16;      // A: 128 rows x 32 k
  const float* Arow = A + (size_t)ar * lda + ak;
  const int bc = tid & 127, bk = (tid >> 7) * 16;    // B: 128 cols x 32 k
  const unsigned short* Bhs = Th + (size_t)bc * ldb + bk;

  f32x4 acc[4][4];
#pragma unroll
  for (int m = 0; m < 4; ++m)
#pragma unroll
    for (int n = 0; n < 4; ++n)
#pragma unroll
      for (int j = 0; j < 4; ++j) acc[m][n][j] = 0.f;

  // 2-deep register pipeline: q* = step t (to stage), p* = step t+1 (in flight)
  float4 qa0 = *(const float4*)(Arow);
  float4 qa1 = *(const float4*)(Arow + 4);
  float4 qa2 = *(const float4*)(Arow + 8);
  float4 qa3 = *(const float4*)(Arow + 12);
  u16x8 qb0 = *(const u16x8*)(Bhs);
  u16x8 qb1 = *(const u16x8*)(Bhs + 8);
  float4 pa0, pa1, pa2, pa3;
  u16x8 pb0, pb1;
  if (nsteps > 1) {
    pa0 = *(const float4*)(Arow + 32);
    pa1 = *(const float4*)(Arow + 36);
    pa2 = *(const float4*)(Arow + 40);
    pa3 = *(const float4*)(Arow + 44);
    pb0 = *(const u16x8*)(Bhs + 32);
    pb1 = *(const u16x8*)(Bhs + 40);
  }

  for (int t = 0; t < nsteps; ++t) {
    {
      float av[16] = {qa0.x, qa0.y, qa0.z, qa0.w, qa1.x, qa1.y, qa1.z, qa1.w,
                      qa2.x, qa2.y, qa2.z, qa2.w, qa3.x, qa3.y, qa3.z, qa3.w};
      u16x8 vh0, vh1, vl0, vl1;
#pragma unroll
      for (int i = 0; i < 16; ++i) {
        float v = av[i];
        if constexpr (NORM) {
          int ch = t * 32 + ak + i;
          v = fmaxf(v * nsc[ch] + nsh[ch], 0.f);
        }
        unsigned short hh, ll;
        split2(v, hh, ll);
        if (i < 8) { vh0[i] = hh; vl0[i] = ll; }
        else       { vh1[i - 8] = hh; vl1[i - 8] = ll; }
      }
      *(u16x8*)&s.Ah[ar][ak]     = vh0;
      *(u16x8*)&s.Ah[ar][ak + 8] = vh1;
      *(u16x8*)&s.Al[ar][ak]     = vl0;
      *(u16x8*)&s.Al[ar][ak + 8] = vl1;
      *(u16x8*)&s.Bh[bc][bk]     = qb0;
      *(u16x8*)&s.Bh[bc][bk + 8] = qb1;
    }
    __syncthreads();
    // rotate pipeline and issue step t+2's loads (2 compute-phases of cover)
    qa0 = pa0; qa1 = pa1; qa2 = pa2; qa3 = pa3;
    qb0 = pb0; qb1 = pb1;
    if (t + 2 < nsteps) {
      const float* An = Arow + (size_t)(t + 2) * 32;
      pa0 = *(const float4*)(An);
      pa1 = *(const float4*)(An + 4);
      pa2 = *(const float4*)(An + 8);
      pa3 = *(const float4*)(An + 12);
      const unsigned short* Bhn = Bhs + (size_t)(t + 2) * 32;
      pb0 = *(const u16x8*)(Bhn);
      pb1 = *(const u16x8*)(Bhn + 8);
    }
    s16x8 fah[4], fal[4], fbh[4];
#pragma unroll
    for (int m = 0; m < 4; ++m) {
      fah[m] = *(const s16x8*)&s.Ah[wr + m * 16 + r][g * 8];
      fal[m] = *(const s16x8*)&s.Al[wr + m * 16 + r][g * 8];
    }
#pragma unroll
    for (int n = 0; n < 4; ++n)
      fbh[n] = *(const s16x8*)&s.Bh[wc + n * 16 + r][g * 8];
#pragma unroll
    for (int m = 0; m < 4; ++m)
#pragma unroll
      for (int n = 0; n < 4; ++n) {
        acc[m][n] = __builtin_amdgcn_mfma_f32_16x16x32_bf16(fal[m], fbh[n], acc[m][n], 0, 0, 0);
        acc[m][n] = __builtin_amdgcn_mfma_f32_16x16x32_bf16(fah[m], fbh[n], acc[m][n], 0, 0, 0);
      }
    __syncthreads();
  }
  // epilogue: C/D layout col=lane&15, row=(lane>>4)*4+reg [m89]
#pragma unroll
  for (int m = 0; m < 4; ++m)
#pragma unroll
    for (int n = 0; n < 4; ++n) {
      int col = wc + n * 16 + r;
      float bv = BIAS ? bias[col] : 0.f;
      int rowb = wr + m * 16 + g * 4;
#pragma unroll
      for (int j = 0; j < 4; ++j) {
        float v = acc[m][n][j] + bv;
        if constexpr (OUTBF) Cb[(size_t)(rowb + j) * 256 + col] = f2bf(v);
        else                 C[(size_t)(rowb + j) * 256 + col] = v;
      }
    }
}

// ---- merged: split-K input projections (blocks 0..511) + attn fill rows 0..4095 ----
#define PDRUG_PLANE ((size_t)2048 * 256)
#define PGENE_PLANE ((size_t)4096 * 256)
__global__ __launch_bounds__(256) void k_inproj_fill(
    const float* __restrict__ drug, const float* __restrict__ cell,
    const float* __restrict__ gene,
    const unsigned short* __restrict__ tdh, const unsigned short* __restrict__ tch,
    const unsigned short* __restrict__ tgh, float* __restrict__ P,
    const int* __restrict__ csrdst, const int* __restrict__ rowst_s,
    float* __restrict__ attn) {
  __shared__ Tile128 s;
  int b = blockIdx.x;
  if (b >= 512) { attn_fill_row(b - 512, csrdst, rowst_s, attn); return; }
  if (b < 256) {          // drug (b<128) / cell: 16 rowblk x 2 colblk x 4 kchunk (K=512)
    int idx = b & 127;
    int colblk = (idx >> 3) & 1;
    int rest = (idx & 7) | ((idx >> 4) << 3);   // 0..63
    int rowblk = rest >> 2, chunk = rest & 3;
    const float* X = (b < 128) ? drug : cell;
    const unsigned short* Th = (b < 128) ? tdh : tch;
    float* Pb = P + ((b < 128) ? 0 : 4 * PDRUG_PLANE);
    gemm_tile128<false, false, false>(s,
        X + (size_t)rowblk * 128 * 2048 + (size_t)chunk * 512, 2048,
        Th + (size_t)colblk * 128 * 2048 + chunk * 512, 2048, 16, nullptr,
        Pb + (size_t)chunk * PDRUG_PLANE + (size_t)rowblk * 128 * 256 + colblk * 128,
        nullptr, nullptr, nullptr);
  } else {                // gene: 32 rowblk x 2 colblk x 4 kchunk (K=1024, 32 steps)
    int idx = b - 256;    // 0..255
    int colblk = (idx >> 3) & 1;
    int rest = (idx & 7) | ((idx >> 4) << 3);   // 0..127
    int rowblk = rest >> 2, chunk = rest & 3;
    gemm_tile128<false, false, false>(s,
        gene + (size_t)rowblk * 128 * 4096 + (size_t)chunk * 1024, 4096,
        tgh + (size_t)colblk * 128 * 4096 + chunk * 1024, 4096, 32, nullptr,
        P + 8 * PDRUG_PLANE + (size_t)chunk * PGENE_PLANE + (size_t)rowblk * 128 * 256 + colblk * 128,
        nullptr, nullptr, nullptr);
  }
}

// reduce partial planes (np=4 uniform) + bias -> bufA [8192, 256]
__global__ __launch_bounds__(256) void k_reduce(const float* __restrict__ P,
    const float* __restrict__ bd, const float* __restrict__ bc,
    const float* __restrict__ bg, float* __restrict__ out) {
  int idx = blockIdx.x * 256 + threadIdx.x;   // float4 index
  size_t e = (size_t)idx * 4;
  int row = (int)(e >> 8);
  int col = (int)(e & 255);
  const float* base; const float* bias; size_t plane;
  if (row < 2048) {
    base = P + (size_t)row * 256 + col; bias = bd; plane = PDRUG_PLANE;
  } else if (row < 4096) {
    base = P + 4 * PDRUG_PLANE + (size_t)(row - 2048) * 256 + col; bias = bc;
    plane = PDRUG_PLANE;
  } else {
    base = P + 8 * PDRUG_PLANE + (size_t)(row - 4096) * 256 + col; bias = bg;
    plane = PGENE_PLANE;
  }
  float4 s = *(const float4*)(base);
#pragma unroll
  for (int p = 1; p < 4; ++p) {
    float4 v = *(const float4*)(base + p * plane);
    s.x += v.x; s.y += v.y; s.z += v.z; s.w += v.w;
  }
  float4 bv = *(const float4*)(bias + col);
  s.x += bv.x; s.y += bv.y; s.z += bv.z; s.w += bv.w;
  *(float4*)(out + e) = s;
}

// merged layer GEMMs (blocks 0..255) + attn fill backfill (blocks 256..1279).
template<bool NORM>
__global__ __launch_bounds__(256) void k_gemm2(const float* __restrict__ A,
    const unsigned short* __restrict__ ThL, const unsigned short* __restrict__ ThR,
    const float* __restrict__ biasL, const float* __restrict__ biasR,
    unsigned short* __restrict__ CLb, unsigned short* __restrict__ CRb,
    const float* __restrict__ csum, const float* __restrict__ csumsq,
    const float* __restrict__ gamma, const float* __restrict__ beta,
    const float* __restrict__ mscale,
    const int* __restrict__ csrdst, const int* __restrict__ rowst_s,
    float* __restrict__ attn, int fill_base) {
  __shared__ TileN s;
  int b = blockIdx.x;
  if (b >= 256) { attn_fill_row(fill_base + b - 256, csrdst, rowst_s, attn); return; }
  int sub = (b >> 3) & 3;
  int x = (b & 7) | ((b >> 5) << 3);     // 0..63
  if constexpr (NORM) {
    int c = threadIdx.x;
    float mu = csum[c] * (1.0f / 8192.0f);
    float ex2 = csumsq[c] * (1.0f / 8192.0f);
    float smu = mscale[c] * mu;
    float var = ex2 - 2.f * smu * mu + smu * smu;
    float sc = rsqrtf(var + 1e-5f) * gamma[c];
    s.nsc[c] = sc;
    s.nsh[c] = beta[c] - smu * sc;
    __syncthreads();
  }
  int row0 = x * 128;
  int col0 = (sub & 1) * 128;
  if (sub >= 2) {
    gemm_tile128<true, true, NORM>(s.t, A + (size_t)row0 * 256, 256,
        ThR + (size_t)col0 * 256, 256, 8,
        biasR + col0, nullptr, CRb + (size_t)row0 * 256 + col0, s.nsc, s.nsh);
  } else {
    gemm_tile128<true, true, NORM>(s.t, A + (size_t)row0 * 256, 256,
        ThL + (size_t)col0 * 256, 256, 8,
        biasL + col0, nullptr, CLb + (size_t)row0 * 256 + col0, s.nsc, s.nsh);
  }
}

// ---------------- dual CSR build (counting sort by dst AND by src) ----------------
__global__ void k_count2(const int* __restrict__ edges, int* __restrict__ cd,
                         int* __restrict__ cs) {
  int e = blockIdx.x * blockDim.x + threadIdx.x;
  if (e >= EETOT) return;
  int s, d;
  if (e < NEDGE) { s = edges[e]; d = edges[NEDGE + e]; } else { s = d = e - NEDGE; }
  atomicAdd(&cd[d], 1);
  atomicAdd(&cs[s], 1);
}

__global__ __launch_bounds__(1024) void k_scan2(
    const int* __restrict__ c0, int* __restrict__ r0, int* __restrict__ u0,
    const int* __restrict__ c1, int* __restrict__ r1, int* __restrict__ u1) {
  const int* counts = blockIdx.x ? c1 : c0;
  int* row_start = blockIdx.x ? r1 : r0;
  int* cursor = blockIdx.x ? u1 : u0;
  __shared__ int part[1024];
  int t = threadIdx.x;
  int base = t * 8;
  int loc[8];
  int s = 0;
#pragma unroll
  for (int j = 0; j < 8; ++j) { loc[j] = s; s += counts[base + j]; }
  part[t] = s;
  __syncthreads();
  for (int off = 1; off < 1024; off <<= 1) {
    int v = (t >= off) ? part[t - off] : 0;
    __syncthreads();
    part[t] += v;
    __syncthreads();
  }
  int pre = (t == 0) ? 0 : part[t - 1];
#pragma unroll
  for (int j = 0; j < 8; ++j) {
    int v = pre + loc[j];
    row_start[base + j] = v;
    cursor[base + j] = v;
  }
  if (t == 1023) row_start[NNODES] = pre + s;
}

__global__ void k_place2(const int* __restrict__ edges, int* __restrict__ curd,
    int* __restrict__ curs, int* __restrict__ csrsrc, int* __restrict__ csrdst) {
  int e = blockIdx.x * blockDim.x + threadIdx.x;
  if (e >= EETOT) return;
  int s, d;
  if (e < NEDGE) { s = edges[e]; d = edges[NEDGE + e]; } else { s = d = e - NEDGE; }
  int pd = atomicAdd(&curd[d], 1);
  csrsrc[pd] = s;                       // src ids ordered by dst (for k_gat)
  int ps = atomicAdd(&curs[s], 1);
  csrdst[ps] = d;                       // dst ids ordered by src (for attnfill)
}

// ---- fused GAT edge phase (blocks 0..2047) + attn fill backfill (2048..3071) ----
__global__ __launch_bounds__(256) void k_gat(
    const unsigned short* __restrict__ xl, const unsigned short* __restrict__ xr,
    const float* __restrict__ att, const int* __restrict__ csrsrc,
    const int* __restrict__ row_start, const float* __restrict__ bias,
    float* __restrict__ out,
    const int* __restrict__ csrdst, const int* __restrict__ rowst_s,
    float* __restrict__ attn, int fill_base) {
  if (blockIdx.x >= 2048) {
    attn_fill_row(fill_base + blockIdx.x - 2048, csrdst, rowst_s, attn);
    return;
  }
  int i = blockIdx.x * 4 + (threadIdx.x >> 6);
  int lane = threadIdx.x & 63;
  int co = (lane >> 4) * 64 + (lane & 15) * 4;   // head*64 + channel
  float4 w4 = *(const float4*)(att + co);
  ushort4 ur = *(const ushort4*)(xr + (size_t)i * 256 + co);
  float4 r4;
  r4.x = bf2f(ur.x); r4.y = bf2f(ur.y); r4.z = bf2f(ur.z); r4.w = bf2f(ur.w);
  float sum = 0.f, ax = 0.f, ay = 0.f, az = 0.f, aw = 0.f;
  int e0 = row_start[i], e1 = row_start[i + 1];   // >=1 edge (self loop)
  int deg = e1 - e0;

  for (int cb = 0; cb < deg; cb += 64) {          // chunks of <=64 edges
    int cn = min(deg - cb, 64);                   // wave-uniform
    int myid = (lane < cn) ? csrsrc[e0 + cb + lane] : 0;
    auto g = [&](int j) {
      int s = __shfl(myid, j);
      return *(const ushort4*)(xl + (size_t)s * 256 + co);
    };
    ushort4 cur[8], nxt[8];
    int curn = min(cn, 8);
#pragma unroll
    for (int j = 0; j < 8; ++j)
      if (j < curn) cur[j] = g(j);
    int p = curn;
    for (;;) {
      int nxtn = min(cn - p, 8);                  // wave-uniform
#pragma unroll
      for (int j = 0; j < 8; ++j)
        if (j < nxtn) nxt[j] = g(p + j);
#pragma unroll
      for (int j = 0; j < 8; ++j) {
        if (j >= curn) break;
        ushort4 u = cur[j];
        float x0 = bf2f(u.x), x1 = bf2f(u.y), x2 = bf2f(u.z), x3 = bf2f(u.w);
        float t = w4.x * lrelu(x0 + r4.x) + w4.y * lrelu(x1 + r4.y) +
                  w4.z * lrelu(x2 + r4.z) + w4.w * lrelu(x3 + r4.w);
        t += __shfl_xor(t, 1);
        t += __shfl_xor(t, 2);
        t += __shfl_xor(t, 4);
        t += __shfl_xor(t, 8);
        float el = __expf(fminf(t, 60.f));
        sum += el;
        ax += el * x0; ay += el * x1; az += el * x2; aw += el * x3;
      }
      if (nxtn <= 0) break;
#pragma unroll
      for (int j = 0; j < 8; ++j) cur[j] = nxt[j];
      curn = nxtn; p += nxtn;
    }
  }
  float inv = 1.0f / sum;
  float4 bv = *(const float4*)(bias + co);
  float4 r;
  r.x = ax * inv + bv.x; r.y = ay * inv + bv.y;
  r.z = az * inv + bv.z; r.w = aw * inv + bv.w;
  *(float4*)(out + (size_t)i * 256 + co) = r;
}

// ---------------- GraphNorm stats (col sum / sumsq) ----------------
__global__ __launch_bounds__(256) void k_colstats(const float* __restrict__ x,
    float* __restrict__ csum, float* __restrict__ csumsq) {
  int c = threadIdx.x;
  int r0 = blockIdx.x * 32;
  float s = 0.f, s2 = 0.f;
  for (int r = 0; r < 32; ++r) {
    float v = x[(size_t)(r0 + r) * 256 + c];
    s += v; s2 += v * v;
  }
  atomicAdd(&csum[c], s);
  atomicAdd(&csumsq[c], s2);
}

// ---------------- pair head with fused GraphNorm+ReLU of the final features -------
__global__ __launch_bounds__(256) void k_pred(const float* __restrict__ h,
    const int* __restrict__ idx_drug, const int* __restrict__ idx_cell,
    const float* __restrict__ W, const float* __restrict__ b,
    const float* __restrict__ csum, const float* __restrict__ csumsq,
    const float* __restrict__ gamma, const float* __restrict__ beta,
    const float* __restrict__ mscale, float* __restrict__ out) {
  int p = blockIdx.x * 4 + (threadIdx.x >> 6);
  if (p >= NPAIRS) return;
  int lane = threadIdx.x & 63;
  int rd = idx_drug[p], rc = idx_cell[p];
  float4 a  = *(const float4*)(h + (size_t)rd * 256 + lane * 4);
  float4 cg = *(const float4*)(h + (size_t)rc * 256 + lane * 4);
  float4 wa = *(const float4*)(W + lane * 4);
  float4 wc = *(const float4*)(W + 256 + lane * 4);
  float av[4] = {a.x, a.y, a.z, a.w};
  float cv[4] = {cg.x, cg.y, cg.z, cg.w};
  float wv[4] = {wa.x, wa.y, wa.z, wa.w};
  float uv[4] = {wc.x, wc.y, wc.z, wc.w};
  float t = 0.f;
#pragma unroll
  for (int j = 0; j < 4; ++j) {
    int ch = lane * 4 + j;
    float mu = csum[ch] * (1.0f / 8192.0f);
    float ex2 = csumsq[ch] * (1.0f / 8192.0f);
    float smu = mscale[ch] * mu;
    float var = ex2 - 2.f * smu * mu + smu * smu;
    float sc = rsqrtf(var + 1e-5f) * gamma[ch];
    float sh = beta[ch] - smu * sc;
    t += fmaxf(av[j] * sc + sh, 0.f) * wv[j] + fmaxf(cv[j] * sc + sh, 0.f) * uv[j];
  }
#pragma unroll
  for (int off = 1; off < 64; off <<= 1) t += __shfl_xor(t, off);
  if (lane == 0) out[p] = 1.0f / (1.0f + __expf(-(t + b[0])));
}

extern "C" void kernel_launch(void* const* d_in, const int* in_sizes, int n_in,
                              void* d_out, int out_size, void* d_ws, size_t ws_size,
                              hipStream_t stream) {
  const float* drug = (const float*)d_in[0];
  const float* cell = (const float*)d_in[1];
  const float* gene = (const float*)d_in[2];
  const int*   edges = (const int*)d_in[3];
  const int*   idxd = (const int*)d_in[4];
  const int*   idxc = (const int*)d_in[5];
  const float* Wd = (const float*)d_in[6];   const float* bd = (const float*)d_in[7];
  const float* Wc = (const float*)d_in[8];   const float* bc = (const float*)d_in[9];
  const float* Wg = (const float*)d_in[10];  const float* bg = (const float*)d_in[11];
  const float* g1Wl = (const float*)d_in[12]; const float* g1bl = (const float*)d_in[13];
  const float* g1Wr = (const float*)d_in[14]; const float* g1br = (const float*)d_in[15];
  const float* g1att = (const float*)d_in[16]; const float* g1bias = (const float*)d_in[17];
  const float* g2Wl = (const float*)d_in[18]; const float* g2bl = (const float*)d_in[19];
  const float* g2Wr = (const float*)d_in[20]; const float* g2br = (const float*)d_in[21];
  const float* g2att = (const float*)d_in[22]; const float* g2bias = (const float*)d_in[23];
  const float* gn1g = (const float*)d_in[24]; const float* gn1b = (const float*)d_in[25];
  const float* gn1s = (const float*)d_in[26];
  const float* gn2g = (const float*)d_in[27]; const float* gn2b = (const float*)d_in[28];
  const float* gn2s = (const float*)d_in[29];
  const float* linW = (const float*)d_in[30]; const float* linb = (const float*)d_in[31];
  float* out = (float*)d_out;
  (void)in_sizes; (void)n_in; (void)out_size; (void)ws_size;

  char* ws = (char*)d_ws;
  size_t off = 0;
  auto take = [&](size_t bytes) -> void* {
    void* p = ws + off;
    off += (bytes + 255) & ~(size_t)255;
    return p;
  };
  float* bufA = (float*)take((size_t)NNODES * 256 * 4);
  unsigned short* bufBb = (unsigned short*)take((size_t)NNODES * 256 * 2);  // xl bf16
  unsigned short* bufCb = (unsigned short*)take((size_t)NNODES * 256 * 2);  // xr bf16
  int* counts_d = (int*)take((size_t)NNODES * 4);
  int* counts_s = (int*)take((size_t)NNODES * 4);
  float* stats  = (float*)take(4 * 256 * 4);     // csum0|csumsq0|csum1|csumsq1
  int* rowst_d  = (int*)take((size_t)(NNODES + 1) * 4);
  int* rowst_s  = (int*)take((size_t)(NNODES + 1) * 4);
  int* cursor_d = (int*)take((size_t)NNODES * 4);
  int* cursor_s = (int*)take((size_t)NNODES * 4);
  int* csrsrc   = (int*)take((size_t)EETOT * 4);
  int* csrdst   = (int*)take((size_t)EETOT * 4);
  unsigned short* tdh = (unsigned short*)take((size_t)256 * 2048 * 2);
  unsigned short* tch = (unsigned short*)take((size_t)256 * 2048 * 2);
  unsigned short* tgh = (unsigned short*)take((size_t)256 * 4096 * 2);
  unsigned short* tl1h = (unsigned short*)take((size_t)256 * 256 * 2);
  unsigned short* tr1h = (unsigned short*)take((size_t)256 * 256 * 2);
  unsigned short* tl2h = (unsigned short*)take((size_t)256 * 256 * 2);
  unsigned short* tr2h = (unsigned short*)take((size_t)256 * 256 * 2);
  float* Ppart = (float*)take((8 * PDRUG_PLANE + 4 * PGENE_PLANE) * 4);
  float* attn = out + NPAIRS;

  // ---- weight transpose (bf16 RNE) + zero-init of counts & stats (one kernel) ----
  k_wsplit_all<<<1152, 256, 0, stream>>>(Wd, Wc, Wg, g1Wl, g1Wr, g2Wl, g2Wr,
      tdh, tch, tgh, tl1h, tr1h, tl2h, tr2h, counts_d, counts_s, stats);

  // ---- dual CSR build ----
  k_count2<<<EETOT / 256, 256, 0, stream>>>(edges, counts_d, counts_s);
  k_scan2<<<2, 1024, 0, stream>>>(counts_d, rowst_d, cursor_d, counts_s, rowst_s, cursor_s);
  k_place2<<<EETOT / 256, 256, 0, stream>>>(edges, cursor_d, cursor_s, csrsrc, csrdst);

  // ---- input projections + attn fill rows 0..4095 ----
  k_inproj_fill<<<512 + 4096, 256, 0, stream>>>(drug, cell, gene, tdh, tch, tgh,
      Ppart, csrdst, rowst_s, attn);
  k_reduce<<<NNODES * 256 / 4 / 256, 256, 0, stream>>>(Ppart, bd, bc, bg, bufA);

  // ---- layer 0 (raw A); fill rows 4096..5119 / 5120..6143 backfilled ----
  k_gemm2<false><<<256 + 1024, 256, 0, stream>>>(bufA, tl1h, tr1h, g1bl, g1br,
      bufBb, bufCb, nullptr, nullptr, nullptr, nullptr, nullptr,
      csrdst, rowst_s, attn, 4096);
  k_gat<<<2048 + 1024, 256, 0, stream>>>(bufBb, bufCb, g1att, csrsrc, rowst_d, g1bias,
      bufA, csrdst, rowst_s, attn, 5120);
  k_colstats<<<NNODES / 32, 256, 0, stream>>>(bufA, stats, stats + 256);

  // ---- layer 1 (GraphNorm+ReLU fused into A-staging); fill rows 6144..8191 ----
  k_gemm2<true><<<256 + 1024, 256, 0, stream>>>(bufA, tl2h, tr2h, g2bl, g2br,
      bufBb, bufCb, stats, stats + 256, gn1g, gn1b, gn1s,
      csrdst, rowst_s, attn, 6144);
  k_gat<<<2048 + 1024, 256, 0, stream>>>(bufBb, bufCb, g2att, csrsrc, rowst_d, g2bias,
      bufA, csrdst, rowst_s, attn, 7168);
  k_colstats<<<NNODES / 32, 256, 0, stream>>>(bufA, stats + 512, stats + 768);

  // ---- pair predictions (final GraphNorm+ReLU fused) -> out[0..9999] ----
  k_pred<<<NPAIRS / 4, 256, 0, stream>>>(bufA, idxd, idxc, linW, linb,
      stats + 512, stats + 768, gn2g, gn2b, gn2s, out);
}

// Round 22
// 273.597 us; speedup vs baseline: 1.0423x; 1.0273x over previous
//
#include <hip/hip_runtime.h>

#define NNODES 8192
#define NEDGE  262144
#define EETOT  270336     // NEDGE + NNODES (self loops appended)
#define NPAIRS 10000

typedef __attribute__((ext_vector_type(8))) short s16x8;
typedef __attribute__((ext_vector_type(8))) unsigned short u16x8;
typedef __attribute__((ext_vector_type(4))) float f32x4;

__device__ __forceinline__ float lrelu(float v) { return v > 0.f ? v : 0.2f * v; }

__device__ __forceinline__ unsigned short f2bf(float f) {   // RNE
  unsigned u = __float_as_uint(f);
  u += 0x7fffu + ((u >> 16) & 1u);
  return (unsigned short)(u >> 16);
}
__device__ __forceinline__ float bf2f(unsigned short u) {
  return __uint_as_float((unsigned)u << 16);
}

// ---- attn row fill: zero 32KB row (NT) + set edge positions; needs src-CSR only ----
__device__ __forceinline__ void attn_fill_row(int row, const int* __restrict__ csrdst,
    const int* __restrict__ rowst_s, float* __restrict__ attn) {
  float* rp = attn + (size_t)row * NNODES;
  f32x4* p4 = (f32x4*)rp;
  f32x4 z = {0.f, 0.f, 0.f, 0.f};
#pragma unroll
  for (int j = 0; j < 8; ++j)
    __builtin_nontemporal_store(z, p4 + j * 256 + threadIdx.x);
  __syncthreads();
  int e0 = rowst_s[row], e1 = rowst_s[row + 1];
  for (int j = e0 + (int)threadIdx.x; j < e1; j += 256)
    rp[csrdst[j]] = 16384.0f / 270336.0f;
}

// ---------------- merged weight pre-transpose (RNE bf16) + zero-init ----------------
__device__ __forceinline__ void wsplit_body(const float* __restrict__ W,
    unsigned short* __restrict__ Th, int K, int blk) {
  int col = threadIdx.x;
  int kb = blk * 8;
  u16x8 vh;
#pragma unroll
  for (int i = 0; i < 8; ++i)
    vh[i] = f2bf(W[(size_t)(kb + i) * 256 + col]);
  *(u16x8*)(Th + (size_t)col * K + kb) = vh;
}

__global__ __launch_bounds__(256) void k_wsplit_all(
    const float* __restrict__ Wd, const float* __restrict__ Wc, const float* __restrict__ Wg,
    const float* __restrict__ W1l, const float* __restrict__ W1r,
    const float* __restrict__ W2l, const float* __restrict__ W2r,
    unsigned short* __restrict__ tdh, unsigned short* __restrict__ tch,
    unsigned short* __restrict__ tgh,
    unsigned short* __restrict__ tl1h, unsigned short* __restrict__ tr1h,
    unsigned short* __restrict__ tl2h, unsigned short* __restrict__ tr2h,
    int* __restrict__ counts_d, int* __restrict__ counts_s, float* __restrict__ stats) {
  int b = blockIdx.x;
  if      (b < 256)  wsplit_body(Wd,  tdh, 2048, b);
  else if (b < 512)  wsplit_body(Wc,  tch, 2048, b - 256);
  else if (b < 1024) wsplit_body(Wg,  tgh, 4096, b - 512);
  else if (b < 1056) { wsplit_body(W1l, tl1h, 256, b - 1024);
                       counts_d[(b - 1024) * 256 + threadIdx.x] = 0; }
  else if (b < 1088) { wsplit_body(W1r, tr1h, 256, b - 1056);
                       counts_s[(b - 1056) * 256 + threadIdx.x] = 0; }
  else if (b < 1120) { wsplit_body(W2l, tl2h, 256, b - 1088);
                       if (b < 1092) stats[(b - 1088) * 256 + threadIdx.x] = 0.f; }
  else               wsplit_body(W2r, tr2h, 256, b - 1120);
}

// ---------------- 128x128 MFMA 1-term bf16 GEMM tile, 2-deep reg pipeline ----------
// acc += Abf@Bbf : A rounded RNE to bf16 in staging (~2^-9 rel, same order as the
// bf16 output rounding already applied to xl/xr). 16 MFMA vs 8 ds_read_b128/step.
struct Tile128 {
  unsigned short Ah[128][40], Bh[128][40];   // +8 pad: bank spread (20 KB)
};
struct TileN {       // NORM variant carries per-channel scale/shift in LDS
  Tile128 t;
  float nsc[256], nsh[256];
};

template<bool BIAS, bool OUTBF, bool NORM>
__device__ __forceinline__ void gemm_tile128(Tile128& s,
    const float* __restrict__ A, int lda,
    const unsigned short* __restrict__ Th, int ldb, int nsteps,
    const float* __restrict__ bias, float* __restrict__ C,
    unsigned short* __restrict__ Cb,
    const float* __restrict__ nsc, const float* __restrict__ nsh) {
  const int tid = threadIdx.x;
  const int wave = tid >> 6, lane = tid & 63;
  const int g = lane >> 4, r = lane & 15;
  const int wr = (wave >> 1) * 64, wc = (wave & 1) * 64;

  const int ar = tid >> 1, ak = (tid & 1) * 16;      // A: 128 rows x 32 k
  const float* Arow = A + (size_t)ar * lda + ak;
  const int bc = tid & 127, bk = (tid >> 7) * 16;    // B: 128 cols x 32 k
  const unsigned short* Bhs = Th + (size_t)bc * ldb + bk;

  f32x4 acc[4][4];
#pragma unroll
  for (int m = 0; m < 4; ++m)
#pragma unroll
    for (int n = 0; n < 4; ++n)
#pragma unroll
      for (int j = 0; j < 4; ++j) acc[m][n][j] = 0.f;

  // 2-deep register pipeline: q* = step t (to stage), p* = step t+1 (in flight)
  float4 qa0 = *(const float4*)(Arow);
  float4 qa1 = *(const float4*)(Arow + 4);
  float4 qa2 = *(const float4*)(Arow + 8);
  float4 qa3 = *(const float4*)(Arow + 12);
  u16x8 qb0 = *(const u16x8*)(Bhs);
  u16x8 qb1 = *(const u16x8*)(Bhs + 8);
  float4 pa0, pa1, pa2, pa3;
  u16x8 pb0, pb1;
  if (nsteps > 1) {
    pa0 = *(const float4*)(Arow + 32);
    pa1 = *(const float4*)(Arow + 36);
    pa2 = *(const float4*)(Arow + 40);
    pa3 = *(const float4*)(Arow + 44);
    pb0 = *(const u16x8*)(Bhs + 32);
    pb1 = *(const u16x8*)(Bhs + 40);
  }

  for (int t = 0; t < nsteps; ++t) {
    {
      float av[16] = {qa0.x, qa0.y, qa0.z, qa0.w, qa1.x, qa1.y, qa1.z, qa1.w,
                      qa2.x, qa2.y, qa2.z, qa2.w, qa3.x, qa3.y, qa3.z, qa3.w};
      u16x8 vh0, vh1;
#pragma unroll
      for (int i = 0; i < 16; ++i) {
        float v = av[i];
        if constexpr (NORM) {
          int ch = t * 32 + ak + i;
          v = fmaxf(v * nsc[ch] + nsh[ch], 0.f);
        }
        unsigned short hh = f2bf(v);
        if (i < 8) vh0[i] = hh;
        else       vh1[i - 8] = hh;
      }
      *(u16x8*)&s.Ah[ar][ak]     = vh0;
      *(u16x8*)&s.Ah[ar][ak + 8] = vh1;
      *(u16x8*)&s.Bh[bc][bk]     = qb0;
      *(u16x8*)&s.Bh[bc][bk + 8] = qb1;
    }
    __syncthreads();
    // rotate pipeline and issue step t+2's loads (2 compute-phases of cover)
    qa0 = pa0; qa1 = pa1; qa2 = pa2; qa3 = pa3;
    qb0 = pb0; qb1 = pb1;
    if (t + 2 < nsteps) {
      const float* An = Arow + (size_t)(t + 2) * 32;
      pa0 = *(const float4*)(An);
      pa1 = *(const float4*)(An + 4);
      pa2 = *(const float4*)(An + 8);
      pa3 = *(const float4*)(An + 12);
      const unsigned short* Bhn = Bhs + (size_t)(t + 2) * 32;
      pb0 = *(const u16x8*)(Bhn);
      pb1 = *(const u16x8*)(Bhn + 8);
    }
    s16x8 fah[4], fbh[4];
#pragma unroll
    for (int m = 0; m < 4; ++m)
      fah[m] = *(const s16x8*)&s.Ah[wr + m * 16 + r][g * 8];
#pragma unroll
    for (int n = 0; n < 4; ++n)
      fbh[n] = *(const s16x8*)&s.Bh[wc + n * 16 + r][g * 8];
#pragma unroll
    for (int m = 0; m < 4; ++m)
#pragma unroll
      for (int n = 0; n < 4; ++n)
        acc[m][n] = __builtin_amdgcn_mfma_f32_16x16x32_bf16(fah[m], fbh[n], acc[m][n], 0, 0, 0);
    __syncthreads();
  }
  // epilogue: C/D layout col=lane&15, row=(lane>>4)*4+reg [m89]
#pragma unroll
  for (int m = 0; m < 4; ++m)
#pragma unroll
    for (int n = 0; n < 4; ++n) {
      int col = wc + n * 16 + r;
      float bv = BIAS ? bias[col] : 0.f;
      int rowb = wr + m * 16 + g * 4;
#pragma unroll
      for (int j = 0; j < 4; ++j) {
        float v = acc[m][n][j] + bv;
        if constexpr (OUTBF) Cb[(size_t)(rowb + j) * 256 + col] = f2bf(v);
        else                 C[(size_t)(rowb + j) * 256 + col] = v;
      }
    }
}

// ---- merged: split-K input projections (blocks 0..511) + attn fill rows 0..4095 ----
#define PDRUG_PLANE ((size_t)2048 * 256)
#define PGENE_PLANE ((size_t)4096 * 256)
__global__ __launch_bounds__(256) void k_inproj_fill(
    const float* __restrict__ drug, const float* __restrict__ cell,
    const float* __restrict__ gene,
    const unsigned short* __restrict__ tdh, const unsigned short* __restrict__ tch,
    const unsigned short* __restrict__ tgh, float* __restrict__ P,
    const int* __restrict__ csrdst, const int* __restrict__ rowst_s,
    float* __restrict__ attn) {
  __shared__ Tile128 s;
  int b = blockIdx.x;
  if (b >= 512) { attn_fill_row(b - 512, csrdst, rowst_s, attn); return; }
  if (b < 256) {          // drug (b<128) / cell: 16 rowblk x 2 colblk x 4 kchunk (K=512)
    int idx = b & 127;
    int colblk = (idx >> 3) & 1;
    int rest = (idx & 7) | ((idx >> 4) << 3);   // 0..63
    int rowblk = rest >> 2, chunk = rest & 3;
    const float* X = (b < 128) ? drug : cell;
    const unsigned short* Th = (b < 128) ? tdh : tch;
    float* Pb = P + ((b < 128) ? 0 : 4 * PDRUG_PLANE);
    gemm_tile128<false, false, false>(s,
        X + (size_t)rowblk * 128 * 2048 + (size_t)chunk * 512, 2048,
        Th + (size_t)colblk * 128 * 2048 + chunk * 512, 2048, 16, nullptr,
        Pb + (size_t)chunk * PDRUG_PLANE + (size_t)rowblk * 128 * 256 + colblk * 128,
        nullptr, nullptr, nullptr);
  } else {                // gene: 32 rowblk x 2 colblk x 4 kchunk (K=1024, 32 steps)
    int idx = b - 256;    // 0..255
    int colblk = (idx >> 3) & 1;
    int rest = (idx & 7) | ((idx >> 4) << 3);   // 0..127
    int rowblk = rest >> 2, chunk = rest & 3;
    gemm_tile128<false, false, false>(s,
        gene + (size_t)rowblk * 128 * 4096 + (size_t)chunk * 1024, 4096,
        tgh + (size_t)colblk * 128 * 4096 + chunk * 1024, 4096, 32, nullptr,
        P + 8 * PDRUG_PLANE + (size_t)chunk * PGENE_PLANE + (size_t)rowblk * 128 * 256 + colblk * 128,
        nullptr, nullptr, nullptr);
  }
}

// reduce partial planes (np=4 uniform) + bias -> bufA [8192, 256]
__global__ __launch_bounds__(256) void k_reduce(const float* __restrict__ P,
    const float* __restrict__ bd, const float* __restrict__ bc,
    const float* __restrict__ bg, float* __restrict__ out) {
  int idx = blockIdx.x * 256 + threadIdx.x;   // float4 index
  size_t e = (size_t)idx * 4;
  int row = (int)(e >> 8);
  int col = (int)(e & 255);
  const float* base; const float* bias; size_t plane;
  if (row < 2048) {
    base = P + (size_t)row * 256 + col; bias = bd; plane = PDRUG_PLANE;
  } else if (row < 4096) {
    base = P + 4 * PDRUG_PLANE + (size_t)(row - 2048) * 256 + col; bias = bc;
    plane = PDRUG_PLANE;
  } else {
    base = P + 8 * PDRUG_PLANE + (size_t)(row - 4096) * 256 + col; bias = bg;
    plane = PGENE_PLANE;
  }
  float4 s = *(const float4*)(base);
#pragma unroll
  for (int p = 1; p < 4; ++p) {
    float4 v = *(const float4*)(base + p * plane);
    s.x += v.x; s.y += v.y; s.z += v.z; s.w += v.w;
  }
  float4 bv = *(const float4*)(bias + col);
  s.x += bv.x; s.y += bv.y; s.z += bv.z; s.w += bv.w;
  *(float4*)(out + e) = s;
}

// merged layer GEMMs (blocks 0..255) + attn fill backfill (blocks 256..1279).
template<bool NORM>
__global__ __launch_bounds__(256) void k_gemm2(const float* __restrict__ A,
    const unsigned short* __restrict__ ThL, const unsigned short* __restrict__ ThR,
    const float* __restrict__ biasL, const float* __restrict__ biasR,
    unsigned short* __restrict__ CLb, unsigned short* __restrict__ CRb,
    const float* __restrict__ csum, const float* __restrict__ csumsq,
    const float* __restrict__ gamma, const float* __restrict__ beta,
    const float* __restrict__ mscale,
    const int* __restrict__ csrdst, const int* __restrict__ rowst_s,
    float* __restrict__ attn, int fill_base) {
  __shared__ TileN s;
  int b = blockIdx.x;
  if (b >= 256) { attn_fill_row(fill_base + b - 256, csrdst, rowst_s, attn); return; }
  int sub = (b >> 3) & 3;
  int x = (b & 7) | ((b >> 5) << 3);     // 0..63
  if constexpr (NORM) {
    int c = threadIdx.x;
    float mu = csum[c] * (1.0f / 8192.0f);
    float ex2 = csumsq[c] * (1.0f / 8192.0f);
    float smu = mscale[c] * mu;
    float var = ex2 - 2.f * smu * mu + smu * smu;
    float sc = rsqrtf(var + 1e-5f) * gamma[c];
    s.nsc[c] = sc;
    s.nsh[c] = beta[c] - smu * sc;
    __syncthreads();
  }
  int row0 = x * 128;
  int col0 = (sub & 1) * 128;
  if (sub >= 2) {
    gemm_tile128<true, true, NORM>(s.t, A + (size_t)row0 * 256, 256,
        ThR + (size_t)col0 * 256, 256, 8,
        biasR + col0, nullptr, CRb + (size_t)row0 * 256 + col0, s.nsc, s.nsh);
  } else {
    gemm_tile128<true, true, NORM>(s.t, A + (size_t)row0 * 256, 256,
        ThL + (size_t)col0 * 256, 256, 8,
        biasL + col0, nullptr, CLb + (size_t)row0 * 256 + col0, s.nsc, s.nsh);
  }
}

// ---------------- dual CSR build (counting sort by dst AND by src) ----------------
__global__ void k_count2(const int* __restrict__ edges, int* __restrict__ cd,
                         int* __restrict__ cs) {
  int e = blockIdx.x * blockDim.x + threadIdx.x;
  if (e >= EETOT) return;
  int s, d;
  if (e < NEDGE) { s = edges[e]; d = edges[NEDGE + e]; } else { s = d = e - NEDGE; }
  atomicAdd(&cd[d], 1);
  atomicAdd(&cs[s], 1);
}

__global__ __launch_bounds__(1024) void k_scan2(
    const int* __restrict__ c0, int* __restrict__ r0, int* __restrict__ u0,
    const int* __restrict__ c1, int* __restrict__ r1, int* __restrict__ u1) {
  const int* counts = blockIdx.x ? c1 : c0;
  int* row_start = blockIdx.x ? r1 : r0;
  int* cursor = blockIdx.x ? u1 : u0;
  __shared__ int part[1024];
  int t = threadIdx.x;
  int base = t * 8;
  int loc[8];
  int s = 0;
#pragma unroll
  for (int j = 0; j < 8; ++j) { loc[j] = s; s += counts[base + j]; }
  part[t] = s;
  __syncthreads();
  for (int off = 1; off < 1024; off <<= 1) {
    int v = (t >= off) ? part[t - off] : 0;
    __syncthreads();
    part[t] += v;
    __syncthreads();
  }
  int pre = (t == 0) ? 0 : part[t - 1];
#pragma unroll
  for (int j = 0; j < 8; ++j) {
    int v = pre + loc[j];
    row_start[base + j] = v;
    cursor[base + j] = v;
  }
  if (t == 1023) row_start[NNODES] = pre + s;
}

__global__ void k_place2(const int* __restrict__ edges, int* __restrict__ curd,
    int* __restrict__ curs, int* __restrict__ csrsrc, int* __restrict__ csrdst) {
  int e = blockIdx.x * blockDim.x + threadIdx.x;
  if (e >= EETOT) return;
  int s, d;
  if (e < NEDGE) { s = edges[e]; d = edges[NEDGE + e]; } else { s = d = e - NEDGE; }
  int pd = atomicAdd(&curd[d], 1);
  csrsrc[pd] = s;                       // src ids ordered by dst (for k_gat)
  int ps = atomicAdd(&curs[s], 1);
  csrdst[ps] = d;                       // dst ids ordered by src (for attnfill)
}

// ---- fused GAT edge phase (blocks 0..2047) + attn fill backfill (2048..3071) ----
__global__ __launch_bounds__(256) void k_gat(
    const unsigned short* __restrict__ xl, const unsigned short* __restrict__ xr,
    const float* __restrict__ att, const int* __restrict__ csrsrc,
    const int* __restrict__ row_start, const float* __restrict__ bias,
    float* __restrict__ out,
    const int* __restrict__ csrdst, const int* __restrict__ rowst_s,
    float* __restrict__ attn, int fill_base) {
  if (blockIdx.x >= 2048) {
    attn_fill_row(fill_base + blockIdx.x - 2048, csrdst, rowst_s, attn);
    return;
  }
  int i = blockIdx.x * 4 + (threadIdx.x >> 6);
  int lane = threadIdx.x & 63;
  int co = (lane >> 4) * 64 + (lane & 15) * 4;   // head*64 + channel
  float4 w4 = *(const float4*)(att + co);
  ushort4 ur = *(const ushort4*)(xr + (size_t)i * 256 + co);
  float4 r4;
  r4.x = bf2f(ur.x); r4.y = bf2f(ur.y); r4.z = bf2f(ur.z); r4.w = bf2f(ur.w);
  float sum = 0.f, ax = 0.f, ay = 0.f, az = 0.f, aw = 0.f;
  int e0 = row_start[i], e1 = row_start[i + 1];   // >=1 edge (self loop)
  int deg = e1 - e0;

  for (int cb = 0; cb < deg; cb += 64) {          // chunks of <=64 edges
    int cn = min(deg - cb, 64);                   // wave-uniform
    int myid = (lane < cn) ? csrsrc[e0 + cb + lane] : 0;
    auto g = [&](int j) {
      int s = __shfl(myid, j);
      return *(const ushort4*)(xl + (size_t)s * 256 + co);
    };
    ushort4 cur[8], nxt[8];
    int curn = min(cn, 8);
#pragma unroll
    for (int j = 0; j < 8; ++j)
      if (j < curn) cur[j] = g(j);
    int p = curn;
    for (;;) {
      int nxtn = min(cn - p, 8);                  // wave-uniform
#pragma unroll
      for (int j = 0; j < 8; ++j)
        if (j < nxtn) nxt[j] = g(p + j);
#pragma unroll
      for (int j = 0; j < 8; ++j) {
        if (j >= curn) break;
        ushort4 u = cur[j];
        float x0 = bf2f(u.x), x1 = bf2f(u.y), x2 = bf2f(u.z), x3 = bf2f(u.w);
        float t = w4.x * lrelu(x0 + r4.x) + w4.y * lrelu(x1 + r4.y) +
                  w4.z * lrelu(x2 + r4.z) + w4.w * lrelu(x3 + r4.w);
        t += __shfl_xor(t, 1);
        t += __shfl_xor(t, 2);
        t += __shfl_xor(t, 4);
        t += __shfl_xor(t, 8);
        float el = __expf(fminf(t, 60.f));
        sum += el;
        ax += el * x0; ay += el * x1; az += el * x2; aw += el * x3;
      }
      if (nxtn <= 0) break;
#pragma unroll
      for (int j = 0; j < 8; ++j) cur[j] = nxt[j];
      curn = nxtn; p += nxtn;
    }
  }
  float inv = 1.0f / sum;
  float4 bv = *(const float4*)(bias + co);
  float4 r;
  r.x = ax * inv + bv.x; r.y = ay * inv + bv.y;
  r.z = az * inv + bv.z; r.w = aw * inv + bv.w;
  *(float4*)(out + (size_t)i * 256 + co) = r;
}

// ---------------- GraphNorm stats (col sum / sumsq) ----------------
__global__ __launch_bounds__(256) void k_colstats(const float* __restrict__ x,
    float* __restrict__ csum, float* __restrict__ csumsq) {
  int c = threadIdx.x;
  int r0 = blockIdx.x * 32;
  float s = 0.f, s2 = 0.f;
  for (int r = 0; r < 32; ++r) {
    float v = x[(size_t)(r0 + r) * 256 + c];
    s += v; s2 += v * v;
  }
  atomicAdd(&csum[c], s);
  atomicAdd(&csumsq[c], s2);
}

// ---------------- pair head with fused GraphNorm+ReLU of the final features -------
__global__ __launch_bounds__(256) void k_pred(const float* __restrict__ h,
    const int* __restrict__ idx_drug, const int* __restrict__ idx_cell,
    const float* __restrict__ W, const float* __restrict__ b,
    const float* __restrict__ csum, const float* __restrict__ csumsq,
    const float* __restrict__ gamma, const float* __restrict__ beta,
    const float* __restrict__ mscale, float* __restrict__ out) {
  int p = blockIdx.x * 4 + (threadIdx.x >> 6);
  if (p >= NPAIRS) return;
  int lane = threadIdx.x & 63;
  int rd = idx_drug[p], rc = idx_cell[p];
  float4 a  = *(const float4*)(h + (size_t)rd * 256 + lane * 4);
  float4 cg = *(const float4*)(h + (size_t)rc * 256 + lane * 4);
  float4 wa = *(const float4*)(W + lane * 4);
  float4 wc = *(const float4*)(W + 256 + lane * 4);
  float av[4] = {a.x, a.y, a.z, a.w};
  float cv[4] = {cg.x, cg.y, cg.z, cg.w};
  float wv[4] = {wa.x, wa.y, wa.z, wa.w};
  float uv[4] = {wc.x, wc.y, wc.z, wc.w};
  float t = 0.f;
#pragma unroll
  for (int j = 0; j < 4; ++j) {
    int ch = lane * 4 + j;
    float mu = csum[ch] * (1.0f / 8192.0f);
    float ex2 = csumsq[ch] * (1.0f / 8192.0f);
    float smu = mscale[ch] * mu;
    float var = ex2 - 2.f * smu * mu + smu * smu;
    float sc = rsqrtf(var + 1e-5f) * gamma[ch];
    float sh = beta[ch] - smu * sc;
    t += fmaxf(av[j] * sc + sh, 0.f) * wv[j] + fmaxf(cv[j] * sc + sh, 0.f) * uv[j];
  }
#pragma unroll
  for (int off = 1; off < 64; off <<= 1) t += __shfl_xor(t, off);
  if (lane == 0) out[p] = 1.0f / (1.0f + __expf(-(t + b[0])));
}

extern "C" void kernel_launch(void* const* d_in, const int* in_sizes, int n_in,
                              void* d_out, int out_size, void* d_ws, size_t ws_size,
                              hipStream_t stream) {
  const float* drug = (const float*)d_in[0];
  const float* cell = (const float*)d_in[1];
  const float* gene = (const float*)d_in[2];
  const int*   edges = (const int*)d_in[3];
  const int*   idxd = (const int*)d_in[4];
  const int*   idxc = (const int*)d_in[5];
  const float* Wd = (const float*)d_in[6];   const float* bd = (const float*)d_in[7];
  const float* Wc = (const float*)d_in[8];   const float* bc = (const float*)d_in[9];
  const float* Wg = (const float*)d_in[10];  const float* bg = (const float*)d_in[11];
  const float* g1Wl = (const float*)d_in[12]; const float* g1bl = (const float*)d_in[13];
  const float* g1Wr = (const float*)d_in[14]; const float* g1br = (const float*)d_in[15];
  const float* g1att = (const float*)d_in[16]; const float* g1bias = (const float*)d_in[17];
  const float* g2Wl = (const float*)d_in[18]; const float* g2bl = (const float*)d_in[19];
  const float* g2Wr = (const float*)d_in[20]; const float* g2br = (const float*)d_in[21];
  const float* g2att = (const float*)d_in[22]; const float* g2bias = (const float*)d_in[23];
  const float* gn1g = (const float*)d_in[24]; const float* gn1b = (const float*)d_in[25];
  const float* gn1s = (const float*)d_in[26];
  const float* gn2g = (const float*)d_in[27]; const float* gn2b = (const float*)d_in[28];
  const float* gn2s = (const float*)d_in[29];
  const float* linW = (const float*)d_in[30]; const float* linb = (const float*)d_in[31];
  float* out = (float*)d_out;
  (void)in_sizes; (void)n_in; (void)out_size; (void)ws_size;

  char* ws = (char*)d_ws;
  size_t off = 0;
  auto take = [&](size_t bytes) -> void* {
    void* p = ws + off;
    off += (bytes + 255) & ~(size_t)255;
    return p;
  };
  float* bufA = (float*)take((size_t)NNODES * 256 * 4);
  unsigned short* bufBb = (unsigned short*)take((size_t)NNODES * 256 * 2);  // xl bf16
  unsigned short* bufCb = (unsigned short*)take((size_t)NNODES * 256 * 2);  // xr bf16
  int* counts_d = (int*)take((size_t)NNODES * 4);
  int* counts_s = (int*)take((size_t)NNODES * 4);
  float* stats  = (float*)take(4 * 256 * 4);     // csum0|csumsq0|csum1|csumsq1
  int* rowst_d  = (int*)take((size_t)(NNODES + 1) * 4);
  int* rowst_s  = (int*)take((size_t)(NNODES + 1) * 4);
  int* cursor_d = (int*)take((size_t)NNODES * 4);
  int* cursor_s = (int*)take((size_t)NNODES * 4);
  int* csrsrc   = (int*)take((size_t)EETOT * 4);
  int* csrdst   = (int*)take((size_t)EETOT * 4);
  unsigned short* tdh = (unsigned short*)take((size_t)256 * 2048 * 2);
  unsigned short* tch = (unsigned short*)take((size_t)256 * 2048 * 2);
  unsigned short* tgh = (unsigned short*)take((size_t)256 * 4096 * 2);
  unsigned short* tl1h = (unsigned short*)take((size_t)256 * 256 * 2);
  unsigned short* tr1h = (unsigned short*)take((size_t)256 * 256 * 2);
  unsigned short* tl2h = (unsigned short*)take((size_t)256 * 256 * 2);
  unsigned short* tr2h = (unsigned short*)take((size_t)256 * 256 * 2);
  float* Ppart = (float*)take((8 * PDRUG_PLANE + 4 * PGENE_PLANE) * 4);
  float* attn = out + NPAIRS;

  // ---- weight transpose (bf16 RNE) + zero-init of counts & stats (one kernel) ----
  k_wsplit_all<<<1152, 256, 0, stream>>>(Wd, Wc, Wg, g1Wl, g1Wr, g2Wl, g2Wr,
      tdh, tch, tgh, tl1h, tr1h, tl2h, tr2h, counts_d, counts_s, stats);

  // ---- dual CSR build ----
  k_count2<<<EETOT / 256, 256, 0, stream>>>(edges, counts_d, counts_s);
  k_scan2<<<2, 1024, 0, stream>>>(counts_d, rowst_d, cursor_d, counts_s, rowst_s, cursor_s);
  k_place2<<<EETOT / 256, 256, 0, stream>>>(edges, cursor_d, cursor_s, csrsrc, csrdst);

  // ---- input projections + attn fill rows 0..4095 ----
  k_inproj_fill<<<512 + 4096, 256, 0, stream>>>(drug, cell, gene, tdh, tch, tgh,
      Ppart, csrdst, rowst_s, attn);
  k_reduce<<<NNODES * 256 / 4 / 256, 256, 0, stream>>>(Ppart, bd, bc, bg, bufA);

  // ---- layer 0 (raw A); fill rows 4096..5119 / 5120..6143 backfilled ----
  k_gemm2<false><<<256 + 1024, 256, 0, stream>>>(bufA, tl1h, tr1h, g1bl, g1br,
      bufBb, bufCb, nullptr, nullptr, nullptr, nullptr, nullptr,
      csrdst, rowst_s, attn, 4096);
  k_gat<<<2048 + 1024, 256, 0, stream>>>(bufBb, bufCb, g1att, csrsrc, rowst_d, g1bias,
      bufA, csrdst, rowst_s, attn, 5120);
  k_colstats<<<NNODES / 32, 256, 0, stream>>>(bufA, stats, stats + 256);

  // ---- layer 1 (GraphNorm+ReLU fused into A-staging); fill rows 6144..8191 ----
  k_gemm2<true><<<256 + 1024, 256, 0, stream>>>(bufA, tl2h, tr2h, g2bl, g2br,
      bufBb, bufCb, stats, stats + 256, gn1g, gn1b, gn1s,
      csrdst, rowst_s, attn, 6144);
  k_gat<<<2048 + 1024, 256, 0, stream>>>(bufBb, bufCb, g2att, csrsrc, rowst_d, g2bias,
      bufA, csrdst, rowst_s, attn, 7168);
  k_colstats<<<NNODES / 32, 256, 0, stream>>>(bufA, stats + 512, stats + 768);

  // ---- pair predictions (final GraphNorm+ReLU fused) -> out[0..9999] ----
  k_pred<<<NPAIRS / 4, 256, 0, stream>>>(bufA, idxd, idxc, linW, linb,
      stats + 512, stats + 768, gn2g, gn2b, gn2s, out);
}

// Round 23
// 270.279 us; speedup vs baseline: 1.0551x; 1.0123x over previous
//
#include <hip/hip_runtime.h>

#define NNODES 8192
#define NEDGE  262144
#define EETOT  270336     // NEDGE + NNODES (self loops appended)
#define NPAIRS 10000

typedef __attribute__((ext_vector_type(8))) short s16x8;
typedef __attribute__((ext_vector_type(8))) unsigned short u16x8;
typedef __attribute__((ext_vector_type(4))) float f32x4;

__device__ __forceinline__ float lrelu(float v) { return v > 0.f ? v : 0.2f * v; }

__device__ __forceinline__ unsigned short f2bf(float f) {   // RNE
  unsigned u = __float_as_uint(f);
  u += 0x7fffu + ((u >> 16) & 1u);
  return (unsigned short)(u >> 16);
}
__device__ __forceinline__ float bf2f(unsigned short u) {
  return __uint_as_float((unsigned)u << 16);
}

// ---- attn row fill: zero 32KB row (NT) + set edge positions; needs src-CSR only ----
__device__ __forceinline__ void attn_fill_row(int row, const int* __restrict__ csrdst,
    const int* __restrict__ rowst_s, float* __restrict__ attn) {
  float* rp = attn + (size_t)row * NNODES;
  f32x4* p4 = (f32x4*)rp;
  f32x4 z = {0.f, 0.f, 0.f, 0.f};
#pragma unroll
  for (int j = 0; j < 8; ++j)
    __builtin_nontemporal_store(z, p4 + j * 256 + threadIdx.x);
  __syncthreads();
  int e0 = rowst_s[row], e1 = rowst_s[row + 1];
  for (int j = e0 + (int)threadIdx.x; j < e1; j += 256)
    rp[csrdst[j]] = 16384.0f / 270336.0f;
}

// ---------------- merged weight pre-transpose (RNE bf16) + zero-init ----------------
__device__ __forceinline__ void wsplit_body(const float* __restrict__ W,
    unsigned short* __restrict__ Th, int K, int blk) {
  int col = threadIdx.x;
  int kb = blk * 8;
  u16x8 vh;
#pragma unroll
  for (int i = 0; i < 8; ++i)
    vh[i] = f2bf(W[(size_t)(kb + i) * 256 + col]);
  *(u16x8*)(Th + (size_t)col * K + kb) = vh;
}

__global__ __launch_bounds__(256) void k_wsplit_all(
    const float* __restrict__ Wd, const float* __restrict__ Wc, const float* __restrict__ Wg,
    const float* __restrict__ W1l, const float* __restrict__ W1r,
    const float* __restrict__ W2l, const float* __restrict__ W2r,
    unsigned short* __restrict__ tdh, unsigned short* __restrict__ tch,
    unsigned short* __restrict__ tgh,
    unsigned short* __restrict__ tl1h, unsigned short* __restrict__ tr1h,
    unsigned short* __restrict__ tl2h, unsigned short* __restrict__ tr2h,
    int* __restrict__ counts_d, int* __restrict__ counts_s, float* __restrict__ stats) {
  int b = blockIdx.x;
  if      (b < 256)  wsplit_body(Wd,  tdh, 2048, b);
  else if (b < 512)  wsplit_body(Wc,  tch, 2048, b - 256);
  else if (b < 1024) wsplit_body(Wg,  tgh, 4096, b - 512);
  else if (b < 1056) { wsplit_body(W1l, tl1h, 256, b - 1024);
                       counts_d[(b - 1024) * 256 + threadIdx.x] = 0; }
  else if (b < 1088) { wsplit_body(W1r, tr1h, 256, b - 1056);
                       counts_s[(b - 1056) * 256 + threadIdx.x] = 0; }
  else if (b < 1120) { wsplit_body(W2l, tl2h, 256, b - 1088);
                       if (b < 1092) stats[(b - 1088) * 256 + threadIdx.x] = 0.f; }
  else               wsplit_body(W2r, tr2h, 256, b - 1120);
}

// ---------------- 128x128 MFMA 1-term bf16 GEMM tile, 2-deep reg pipeline ----------
// ABF: A operand already bf16 (direct LDS copy unless NORM rescales it).
struct Tile128 {
  unsigned short Ah[128][40], Bh[128][40];   // +8 pad: bank spread (20 KB)
};
struct TileN {       // NORM variant carries per-channel scale/shift in LDS
  Tile128 t;
  float nsc[256], nsh[256];
};

template<bool BIAS, bool OUTBF, bool NORM, bool ABF>
__device__ __forceinline__ void gemm_tile128(Tile128& s,
    const void* __restrict__ Av, int lda,
    const unsigned short* __restrict__ Th, int ldb, int nsteps,
    const float* __restrict__ bias, float* __restrict__ C,
    unsigned short* __restrict__ Cb,
    const float* __restrict__ nsc, const float* __restrict__ nsh) {
  const int tid = threadIdx.x;
  const int wave = tid >> 6, lane = tid & 63;
  const int g = lane >> 4, r = lane & 15;
  const int wr = (wave >> 1) * 64, wc = (wave & 1) * 64;

  const int ar = tid >> 1, ak = (tid & 1) * 16;      // A: 128 rows x 32 k
  const float* ArowF = (const float*)Av + (size_t)ar * lda + ak;
  const unsigned short* ArowB = (const unsigned short*)Av + (size_t)ar * lda + ak;
  const int bc = tid & 127, bk = (tid >> 7) * 16;    // B: 128 cols x 32 k
  const unsigned short* Bhs = Th + (size_t)bc * ldb + bk;

  f32x4 acc[4][4];
#pragma unroll
  for (int m = 0; m < 4; ++m)
#pragma unroll
    for (int n = 0; n < 4; ++n)
#pragma unroll
      for (int j = 0; j < 4; ++j) acc[m][n][j] = 0.f;

  // 2-deep register pipeline: q* = step t (to stage), p* = step t+1 (in flight)
  float4 qa0, qa1, qa2, qa3, pa0, pa1, pa2, pa3;
  u16x8 qA0, qA1, pA0, pA1;
  if constexpr (ABF) {
    qA0 = *(const u16x8*)(ArowB);
    qA1 = *(const u16x8*)(ArowB + 8);
  } else {
    qa0 = *(const float4*)(ArowF);
    qa1 = *(const float4*)(ArowF + 4);
    qa2 = *(const float4*)(ArowF + 8);
    qa3 = *(const float4*)(ArowF + 12);
  }
  u16x8 qb0 = *(const u16x8*)(Bhs);
  u16x8 qb1 = *(const u16x8*)(Bhs + 8);
  u16x8 pb0, pb1;
  if (nsteps > 1) {
    if constexpr (ABF) {
      pA0 = *(const u16x8*)(ArowB + 32);
      pA1 = *(const u16x8*)(ArowB + 40);
    } else {
      pa0 = *(const float4*)(ArowF + 32);
      pa1 = *(const float4*)(ArowF + 36);
      pa2 = *(const float4*)(ArowF + 40);
      pa3 = *(const float4*)(ArowF + 44);
    }
    pb0 = *(const u16x8*)(Bhs + 32);
    pb1 = *(const u16x8*)(Bhs + 40);
  }

  for (int t = 0; t < nsteps; ++t) {
    if constexpr (ABF) {
      if constexpr (NORM) {
        u16x8 vh0, vh1;
#pragma unroll
        for (int i = 0; i < 8; ++i) {
          int ch = t * 32 + ak + i;
          float v = fmaxf(bf2f(qA0[i]) * nsc[ch] + nsh[ch], 0.f);
          vh0[i] = f2bf(v);
          int ch2 = ch + 8;
          float v2 = fmaxf(bf2f(qA1[i]) * nsc[ch2] + nsh[ch2], 0.f);
          vh1[i] = f2bf(v2);
        }
        *(u16x8*)&s.Ah[ar][ak]     = vh0;
        *(u16x8*)&s.Ah[ar][ak + 8] = vh1;
      } else {
        *(u16x8*)&s.Ah[ar][ak]     = qA0;
        *(u16x8*)&s.Ah[ar][ak + 8] = qA1;
      }
    } else {
      float av[16] = {qa0.x, qa0.y, qa0.z, qa0.w, qa1.x, qa1.y, qa1.z, qa1.w,
                      qa2.x, qa2.y, qa2.z, qa2.w, qa3.x, qa3.y, qa3.z, qa3.w};
      u16x8 vh0, vh1;
#pragma unroll
      for (int i = 0; i < 16; ++i) {
        unsigned short hh = f2bf(av[i]);
        if (i < 8) vh0[i] = hh;
        else       vh1[i - 8] = hh;
      }
      *(u16x8*)&s.Ah[ar][ak]     = vh0;
      *(u16x8*)&s.Ah[ar][ak + 8] = vh1;
    }
    *(u16x8*)&s.Bh[bc][bk]     = qb0;
    *(u16x8*)&s.Bh[bc][bk + 8] = qb1;
    __syncthreads();
    // rotate pipeline and issue step t+2's loads (2 compute-phases of cover)
    if constexpr (ABF) { qA0 = pA0; qA1 = pA1; }
    else { qa0 = pa0; qa1 = pa1; qa2 = pa2; qa3 = pa3; }
    qb0 = pb0; qb1 = pb1;
    if (t + 2 < nsteps) {
      if constexpr (ABF) {
        const unsigned short* An = ArowB + (size_t)(t + 2) * 32;
        pA0 = *(const u16x8*)(An);
        pA1 = *(const u16x8*)(An + 8);
      } else {
        const float* An = ArowF + (size_t)(t + 2) * 32;
        pa0 = *(const float4*)(An);
        pa1 = *(const float4*)(An + 4);
        pa2 = *(const float4*)(An + 8);
        pa3 = *(const float4*)(An + 12);
      }
      const unsigned short* Bhn = Bhs + (size_t)(t + 2) * 32;
      pb0 = *(const u16x8*)(Bhn);
      pb1 = *(const u16x8*)(Bhn + 8);
    }
    s16x8 fah[4], fbh[4];
#pragma unroll
    for (int m = 0; m < 4; ++m)
      fah[m] = *(const s16x8*)&s.Ah[wr + m * 16 + r][g * 8];
#pragma unroll
    for (int n = 0; n < 4; ++n)
      fbh[n] = *(const s16x8*)&s.Bh[wc + n * 16 + r][g * 8];
#pragma unroll
    for (int m = 0; m < 4; ++m)
#pragma unroll
      for (int n = 0; n < 4; ++n)
        acc[m][n] = __builtin_amdgcn_mfma_f32_16x16x32_bf16(fah[m], fbh[n], acc[m][n], 0, 0, 0);
    __syncthreads();
  }
  // epilogue: C/D layout col=lane&15, row=(lane>>4)*4+reg [m89]
#pragma unroll
  for (int m = 0; m < 4; ++m)
#pragma unroll
    for (int n = 0; n < 4; ++n) {
      int col = wc + n * 16 + r;
      float bv = BIAS ? bias[col] : 0.f;
      int rowb = wr + m * 16 + g * 4;
#pragma unroll
      for (int j = 0; j < 4; ++j) {
        float v = acc[m][n][j] + bv;
        if constexpr (OUTBF) Cb[(size_t)(rowb + j) * 256 + col] = f2bf(v);
        else                 C[(size_t)(rowb + j) * 256 + col] = v;
      }
    }
}

// ---- merged: split-K input projections (blocks 0..511) + attn fill rows 0..4095 ----
#define PDRUG_PLANE ((size_t)2048 * 256)
#define PGENE_PLANE ((size_t)4096 * 256)
__global__ __launch_bounds__(256) void k_inproj_fill(
    const float* __restrict__ drug, const float* __restrict__ cell,
    const float* __restrict__ gene,
    const unsigned short* __restrict__ tdh, const unsigned short* __restrict__ tch,
    const unsigned short* __restrict__ tgh, float* __restrict__ P,
    const int* __restrict__ csrdst, const int* __restrict__ rowst_s,
    float* __restrict__ attn) {
  __shared__ Tile128 s;
  int b = blockIdx.x;
  if (b >= 512) { attn_fill_row(b - 512, csrdst, rowst_s, attn); return; }
  if (b < 256) {          // drug (b<128) / cell: 16 rowblk x 2 colblk x 4 kchunk (K=512)
    int idx = b & 127;
    int colblk = (idx >> 3) & 1;
    int rest = (idx & 7) | ((idx >> 4) << 3);   // 0..63
    int rowblk = rest >> 2, chunk = rest & 3;
    const float* X = (b < 128) ? drug : cell;
    const unsigned short* Th = (b < 128) ? tdh : tch;
    float* Pb = P + ((b < 128) ? 0 : 4 * PDRUG_PLANE);
    gemm_tile128<false, false, false, false>(s,
        X + (size_t)rowblk * 128 * 2048 + (size_t)chunk * 512, 2048,
        Th + (size_t)colblk * 128 * 2048 + chunk * 512, 2048, 16, nullptr,
        Pb + (size_t)chunk * PDRUG_PLANE + (size_t)rowblk * 128 * 256 + colblk * 128,
        nullptr, nullptr, nullptr);
  } else {                // gene: 32 rowblk x 2 colblk x 4 kchunk (K=1024, 32 steps)
    int idx = b - 256;    // 0..255
    int colblk = (idx >> 3) & 1;
    int rest = (idx & 7) | ((idx >> 4) << 3);   // 0..127
    int rowblk = rest >> 2, chunk = rest & 3;
    gemm_tile128<false, false, false, false>(s,
        gene + (size_t)rowblk * 128 * 4096 + (size_t)chunk * 1024, 4096,
        tgh + (size_t)colblk * 128 * 4096 + chunk * 1024, 4096, 32, nullptr,
        P + 8 * PDRUG_PLANE + (size_t)chunk * PGENE_PLANE + (size_t)rowblk * 128 * 256 + colblk * 128,
        nullptr, nullptr, nullptr);
  }
}

// reduce partial planes (np=4 uniform) + bias -> bufAb [8192, 256] bf16
__global__ __launch_bounds__(256) void k_reduce(const float* __restrict__ P,
    const float* __restrict__ bd, const float* __restrict__ bc,
    const float* __restrict__ bg, unsigned short* __restrict__ out) {
  int idx = blockIdx.x * 256 + threadIdx.x;   // float4 index
  size_t e = (size_t)idx * 4;
  int row = (int)(e >> 8);
  int col = (int)(e & 255);
  const float* base; const float* bias; size_t plane;
  if (row < 2048) {
    base = P + (size_t)row * 256 + col; bias = bd; plane = PDRUG_PLANE;
  } else if (row < 4096) {
    base = P + 4 * PDRUG_PLANE + (size_t)(row - 2048) * 256 + col; bias = bc;
    plane = PDRUG_PLANE;
  } else {
    base = P + 8 * PDRUG_PLANE + (size_t)(row - 4096) * 256 + col; bias = bg;
    plane = PGENE_PLANE;
  }
  float4 s = *(const float4*)(base);
#pragma unroll
  for (int p = 1; p < 4; ++p) {
    float4 v = *(const float4*)(base + p * plane);
    s.x += v.x; s.y += v.y; s.z += v.z; s.w += v.w;
  }
  float4 bv = *(const float4*)(bias + col);
  ushort4 r;
  r.x = f2bf(s.x + bv.x); r.y = f2bf(s.y + bv.y);
  r.z = f2bf(s.z + bv.z); r.w = f2bf(s.w + bv.w);
  *(ushort4*)(out + e) = r;
}

// merged layer GEMMs (blocks 0..255) + attn fill backfill (blocks 256..1279).
template<bool NORM>
__global__ __launch_bounds__(256) void k_gemm2(const unsigned short* __restrict__ A,
    const unsigned short* __restrict__ ThL, const unsigned short* __restrict__ ThR,
    const float* __restrict__ biasL, const float* __restrict__ biasR,
    unsigned short* __restrict__ CLb, unsigned short* __restrict__ CRb,
    const float* __restrict__ csum, const float* __restrict__ csumsq,
    const float* __restrict__ gamma, const float* __restrict__ beta,
    const float* __restrict__ mscale,
    const int* __restrict__ csrdst, const int* __restrict__ rowst_s,
    float* __restrict__ attn, int fill_base) {
  __shared__ TileN s;
  int b = blockIdx.x;
  if (b >= 256) { attn_fill_row(fill_base + b - 256, csrdst, rowst_s, attn); return; }
  int sub = (b >> 3) & 3;
  int x = (b & 7) | ((b >> 5) << 3);     // 0..63
  if constexpr (NORM) {
    int c = threadIdx.x;
    float mu = csum[c] * (1.0f / 8192.0f);
    float ex2 = csumsq[c] * (1.0f / 8192.0f);
    float smu = mscale[c] * mu;
    float var = ex2 - 2.f * smu * mu + smu * smu;
    float sc = rsqrtf(var + 1e-5f) * gamma[c];
    s.nsc[c] = sc;
    s.nsh[c] = beta[c] - smu * sc;
    __syncthreads();
  }
  int row0 = x * 128;
  int col0 = (sub & 1) * 128;
  if (sub >= 2) {
    gemm_tile128<true, true, NORM, true>(s.t, A + (size_t)row0 * 256, 256,
        ThR + (size_t)col0 * 256, 256, 8,
        biasR + col0, nullptr, CRb + (size_t)row0 * 256 + col0, s.nsc, s.nsh);
  } else {
    gemm_tile128<true, true, NORM, true>(s.t, A + (size_t)row0 * 256, 256,
        ThL + (size_t)col0 * 256, 256, 8,
        biasL + col0, nullptr, CLb + (size_t)row0 * 256 + col0, s.nsc, s.nsh);
  }
}

// ---------------- dual CSR build (counting sort by dst AND by src) ----------------
__global__ void k_count2(const int* __restrict__ edges, int* __restrict__ cd,
                         int* __restrict__ cs) {
  int e = blockIdx.x * blockDim.x + threadIdx.x;
  if (e >= EETOT) return;
  int s, d;
  if (e < NEDGE) { s = edges[e]; d = edges[NEDGE + e]; } else { s = d = e - NEDGE; }
  atomicAdd(&cd[d], 1);
  atomicAdd(&cs[s], 1);
}

__global__ __launch_bounds__(1024) void k_scan2(
    const int* __restrict__ c0, int* __restrict__ r0, int* __restrict__ u0,
    const int* __restrict__ c1, int* __restrict__ r1, int* __restrict__ u1) {
  const int* counts = blockIdx.x ? c1 : c0;
  int* row_start = blockIdx.x ? r1 : r0;
  int* cursor = blockIdx.x ? u1 : u0;
  __shared__ int part[1024];
  int t = threadIdx.x;
  int base = t * 8;
  int loc[8];
  int s = 0;
#pragma unroll
  for (int j = 0; j < 8; ++j) { loc[j] = s; s += counts[base + j]; }
  part[t] = s;
  __syncthreads();
  for (int off = 1; off < 1024; off <<= 1) {
    int v = (t >= off) ? part[t - off] : 0;
    __syncthreads();
    part[t] += v;
    __syncthreads();
  }
  int pre = (t == 0) ? 0 : part[t - 1];
#pragma unroll
  for (int j = 0; j < 8; ++j) {
    int v = pre + loc[j];
    row_start[base + j] = v;
    cursor[base + j] = v;
  }
  if (t == 1023) row_start[NNODES] = pre + s;
}

__global__ void k_place2(const int* __restrict__ edges, int* __restrict__ curd,
    int* __restrict__ curs, int* __restrict__ csrsrc, int* __restrict__ csrdst) {
  int e = blockIdx.x * blockDim.x + threadIdx.x;
  if (e >= EETOT) return;
  int s, d;
  if (e < NEDGE) { s = edges[e]; d = edges[NEDGE + e]; } else { s = d = e - NEDGE; }
  int pd = atomicAdd(&curd[d], 1);
  csrsrc[pd] = s;                       // src ids ordered by dst (for k_gat)
  int ps = atomicAdd(&curs[s], 1);
  csrdst[ps] = d;                       // dst ids ordered by src (for attnfill)
}

// ---- fused GAT edge phase (blocks 0..2047) + attn fill backfill (2048..3071) ----
__global__ __launch_bounds__(256) void k_gat(
    const unsigned short* __restrict__ xl, const unsigned short* __restrict__ xr,
    const float* __restrict__ att, const int* __restrict__ csrsrc,
    const int* __restrict__ row_start, const float* __restrict__ bias,
    unsigned short* __restrict__ out,
    const int* __restrict__ csrdst, const int* __restrict__ rowst_s,
    float* __restrict__ attn, int fill_base) {
  if (blockIdx.x >= 2048) {
    attn_fill_row(fill_base + blockIdx.x - 2048, csrdst, rowst_s, attn);
    return;
  }
  int i = blockIdx.x * 4 + (threadIdx.x >> 6);
  int lane = threadIdx.x & 63;
  int co = (lane >> 4) * 64 + (lane & 15) * 4;   // head*64 + channel
  float4 w4 = *(const float4*)(att + co);
  ushort4 ur = *(const ushort4*)(xr + (size_t)i * 256 + co);
  float4 r4;
  r4.x = bf2f(ur.x); r4.y = bf2f(ur.y); r4.z = bf2f(ur.z); r4.w = bf2f(ur.w);
  float sum = 0.f, ax = 0.f, ay = 0.f, az = 0.f, aw = 0.f;
  int e0 = row_start[i], e1 = row_start[i + 1];   // >=1 edge (self loop)
  int deg = e1 - e0;

  for (int cb = 0; cb < deg; cb += 64) {          // chunks of <=64 edges
    int cn = min(deg - cb, 64);                   // wave-uniform
    int myid = (lane < cn) ? csrsrc[e0 + cb + lane] : 0;
    auto g = [&](int j) {
      int s = __shfl(myid, j);
      return *(const ushort4*)(xl + (size_t)s * 256 + co);
    };
    ushort4 cur[8], nxt[8];
    int curn = min(cn, 8);
#pragma unroll
    for (int j = 0; j < 8; ++j)
      if (j < curn) cur[j] = g(j);
    int p = curn;
    for (;;) {
      int nxtn = min(cn - p, 8);                  // wave-uniform
#pragma unroll
      for (int j = 0; j < 8; ++j)
        if (j < nxtn) nxt[j] = g(p + j);
#pragma unroll
      for (int j = 0; j < 8; ++j) {
        if (j >= curn) break;
        ushort4 u = cur[j];
        float x0 = bf2f(u.x), x1 = bf2f(u.y), x2 = bf2f(u.z), x3 = bf2f(u.w);
        float t = w4.x * lrelu(x0 + r4.x) + w4.y * lrelu(x1 + r4.y) +
                  w4.z * lrelu(x2 + r4.z) + w4.w * lrelu(x3 + r4.w);
        t += __shfl_xor(t, 1);
        t += __shfl_xor(t, 2);
        t += __shfl_xor(t, 4);
        t += __shfl_xor(t, 8);
        float el = __expf(fminf(t, 60.f));
        sum += el;
        ax += el * x0; ay += el * x1; az += el * x2; aw += el * x3;
      }
      if (nxtn <= 0) break;
#pragma unroll
      for (int j = 0; j < 8; ++j) cur[j] = nxt[j];
      curn = nxtn; p += nxtn;
    }
  }
  float inv = 1.0f / sum;
  float4 bv = *(const float4*)(bias + co);
  ushort4 r;
  r.x = f2bf(ax * inv + bv.x); r.y = f2bf(ay * inv + bv.y);
  r.z = f2bf(az * inv + bv.z); r.w = f2bf(aw * inv + bv.w);
  *(ushort4*)(out + (size_t)i * 256 + co) = r;
}

// ---------------- GraphNorm stats (col sum / sumsq), bf16 input ----------------
__global__ __launch_bounds__(256) void k_colstats(const unsigned short* __restrict__ x,
    float* __restrict__ csum, float* __restrict__ csumsq) {
  int c = threadIdx.x;
  int r0 = blockIdx.x * 32;
  float s = 0.f, s2 = 0.f;
  for (int r = 0; r < 32; ++r) {
    float v = bf2f(x[(size_t)(r0 + r) * 256 + c]);
    s += v; s2 += v * v;
  }
  atomicAdd(&csum[c], s);
  atomicAdd(&csumsq[c], s2);
}

// ---------------- pair head with fused GraphNorm+ReLU of the final features -------
__global__ __launch_bounds__(256) void k_pred(const unsigned short* __restrict__ h,
    const int* __restrict__ idx_drug, const int* __restrict__ idx_cell,
    const float* __restrict__ W, const float* __restrict__ b,
    const float* __restrict__ csum, const float* __restrict__ csumsq,
    const float* __restrict__ gamma, const float* __restrict__ beta,
    const float* __restrict__ mscale, float* __restrict__ out) {
  int p = blockIdx.x * 4 + (threadIdx.x >> 6);
  if (p >= NPAIRS) return;
  int lane = threadIdx.x & 63;
  int rd = idx_drug[p], rc = idx_cell[p];
  ushort4 a  = *(const ushort4*)(h + (size_t)rd * 256 + lane * 4);
  ushort4 cg = *(const ushort4*)(h + (size_t)rc * 256 + lane * 4);
  float4 wa = *(const float4*)(W + lane * 4);
  float4 wc = *(const float4*)(W + 256 + lane * 4);
  float av[4] = {bf2f(a.x), bf2f(a.y), bf2f(a.z), bf2f(a.w)};
  float cv[4] = {bf2f(cg.x), bf2f(cg.y), bf2f(cg.z), bf2f(cg.w)};
  float wv[4] = {wa.x, wa.y, wa.z, wa.w};
  float uv[4] = {wc.x, wc.y, wc.z, wc.w};
  float t = 0.f;
#pragma unroll
  for (int j = 0; j < 4; ++j) {
    int ch = lane * 4 + j;
    float mu = csum[ch] * (1.0f / 8192.0f);
    float ex2 = csumsq[ch] * (1.0f / 8192.0f);
    float smu = mscale[ch] * mu;
    float var = ex2 - 2.f * smu * mu + smu * smu;
    float sc = rsqrtf(var + 1e-5f) * gamma[ch];
    float sh = beta[ch] - smu * sc;
    t += fmaxf(av[j] * sc + sh, 0.f) * wv[j] + fmaxf(cv[j] * sc + sh, 0.f) * uv[j];
  }
#pragma unroll
  for (int off = 1; off < 64; off <<= 1) t += __shfl_xor(t, off);
  if (lane == 0) out[p] = 1.0f / (1.0f + __expf(-(t + b[0])));
}

extern "C" void kernel_launch(void* const* d_in, const int* in_sizes, int n_in,
                              void* d_out, int out_size, void* d_ws, size_t ws_size,
                              hipStream_t stream) {
  const float* drug = (const float*)d_in[0];
  const float* cell = (const float*)d_in[1];
  const float* gene = (const float*)d_in[2];
  const int*   edges = (const int*)d_in[3];
  const int*   idxd = (const int*)d_in[4];
  const int*   idxc = (const int*)d_in[5];
  const float* Wd = (const float*)d_in[6];   const float* bd = (const float*)d_in[7];
  const float* Wc = (const float*)d_in[8];   const float* bc = (const float*)d_in[9];
  const float* Wg = (const float*)d_in[10];  const float* bg = (const float*)d_in[11];
  const float* g1Wl = (const float*)d_in[12]; const float* g1bl = (const float*)d_in[13];
  const float* g1Wr = (const float*)d_in[14]; const float* g1br = (const float*)d_in[15];
  const float* g1att = (const float*)d_in[16]; const float* g1bias = (const float*)d_in[17];
  const float* g2Wl = (const float*)d_in[18]; const float* g2bl = (const float*)d_in[19];
  const float* g2Wr = (const float*)d_in[20]; const float* g2br = (const float*)d_in[21];
  const float* g2att = (const float*)d_in[22]; const float* g2bias = (const float*)d_in[23];
  const float* gn1g = (const float*)d_in[24]; const float* gn1b = (const float*)d_in[25];
  const float* gn1s = (const float*)d_in[26];
  const float* gn2g = (const float*)d_in[27]; const float* gn2b = (const float*)d_in[28];
  const float* gn2s = (const float*)d_in[29];
  const float* linW = (const float*)d_in[30]; const float* linb = (const float*)d_in[31];
  float* out = (float*)d_out;
  (void)in_sizes; (void)n_in; (void)out_size; (void)ws_size;

  char* ws = (char*)d_ws;
  size_t off = 0;
  auto take = [&](size_t bytes) -> void* {
    void* p = ws + off;
    off += (bytes + 255) & ~(size_t)255;
    return p;
  };
  unsigned short* bufAb = (unsigned short*)take((size_t)NNODES * 256 * 2);  // features bf16
  unsigned short* bufBb = (unsigned short*)take((size_t)NNODES * 256 * 2);  // xl bf16
  unsigned short* bufCb = (unsigned short*)take((size_t)NNODES * 256 * 2);  // xr bf16
  int* counts_d = (int*)take((size_t)NNODES * 4);
  int* counts_s = (int*)take((size_t)NNODES * 4);
  float* stats  = (float*)take(4 * 256 * 4);     // csum0|csumsq0|csum1|csumsq1
  int* rowst_d  = (int*)take((size_t)(NNODES + 1) * 4);
  int* rowst_s  = (int*)take((size_t)(NNODES + 1) * 4);
  int* cursor_d = (int*)take((size_t)NNODES * 4);
  int* cursor_s = (int*)take((size_t)NNODES * 4);
  int* csrsrc   = (int*)take((size_t)EETOT * 4);
  int* csrdst   = (int*)take((size_t)EETOT * 4);
  unsigned short* tdh = (unsigned short*)take((size_t)256 * 2048 * 2);
  unsigned short* tch = (unsigned short*)take((size_t)256 * 2048 * 2);
  unsigned short* tgh = (unsigned short*)take((size_t)256 * 4096 * 2);
  unsigned short* tl1h = (unsigned short*)take((size_t)256 * 256 * 2);
  unsigned short* tr1h = (unsigned short*)take((size_t)256 * 256 * 2);
  unsigned short* tl2h = (unsigned short*)take((size_t)256 * 256 * 2);
  unsigned short* tr2h = (unsigned short*)take((size_t)256 * 256 * 2);
  float* Ppart = (float*)take((8 * PDRUG_PLANE + 4 * PGENE_PLANE) * 4);
  float* attn = out + NPAIRS;

  // ---- weight transpose (bf16 RNE) + zero-init of counts & stats (one kernel) ----
  k_wsplit_all<<<1152, 256, 0, stream>>>(Wd, Wc, Wg, g1Wl, g1Wr, g2Wl, g2Wr,
      tdh, tch, tgh, tl1h, tr1h, tl2h, tr2h, counts_d, counts_s, stats);

  // ---- dual CSR build ----
  k_count2<<<EETOT / 256, 256, 0, stream>>>(edges, counts_d, counts_s);
  k_scan2<<<2, 1024, 0, stream>>>(counts_d, rowst_d, cursor_d, counts_s, rowst_s, cursor_s);
  k_place2<<<EETOT / 256, 256, 0, stream>>>(edges, cursor_d, cursor_s, csrsrc, csrdst);

  // ---- input projections + attn fill rows 0..4095 ----
  k_inproj_fill<<<512 + 4096, 256, 0, stream>>>(drug, cell, gene, tdh, tch, tgh,
      Ppart, csrdst, rowst_s, attn);
  k_reduce<<<NNODES * 256 / 4 / 256, 256, 0, stream>>>(Ppart, bd, bc, bg, bufAb);

  // ---- layer 0 (raw A); fill rows 4096..5119 / 5120..6143 backfilled ----
  k_gemm2<false><<<256 + 1024, 256, 0, stream>>>(bufAb, tl1h, tr1h, g1bl, g1br,
      bufBb, bufCb, nullptr, nullptr, nullptr, nullptr, nullptr,
      csrdst, rowst_s, attn, 4096);
  k_gat<<<2048 + 1024, 256, 0, stream>>>(bufBb, bufCb, g1att, csrsrc, rowst_d, g1bias,
      bufAb, csrdst, rowst_s, attn, 5120);
  k_colstats<<<NNODES / 32, 256, 0, stream>>>(bufAb, stats, stats + 256);

  // ---- layer 1 (GraphNorm+ReLU fused into A-staging); fill rows 6144..8191 ----
  k_gemm2<true><<<256 + 1024, 256, 0, stream>>>(bufAb, tl2h, tr2h, g2bl, g2br,
      bufBb, bufCb, stats, stats + 256, gn1g, gn1b, gn1s,
      csrdst, rowst_s, attn, 6144);
  k_gat<<<2048 + 1024, 256, 0, stream>>>(bufBb, bufCb, g2att, csrsrc, rowst_d, g2bias,
      bufAb, csrdst, rowst_s, attn, 7168);
  k_colstats<<<NNODES / 32, 256, 0, stream>>>(bufAb, stats + 512, stats + 768);

  // ---- pair predictions (final GraphNorm+ReLU fused) -> out[0..9999] ----
  k_pred<<<NPAIRS / 4, 256, 0, stream>>>(bufAb, idxd, idxc, linW, linb,
      stats + 512, stats + 768, gn2g, gn2b, gn2s, out);
}

// Round 24
// 266.732 us; speedup vs baseline: 1.0691x; 1.0133x over previous
//
#include <hip/hip_runtime.h>

#define NNODES 8192
#define NEDGE  262144
#define EETOT  270336     // NEDGE + NNODES (self loops appended)
#define NPAIRS 10000

typedef __attribute__((ext_vector_type(8))) short s16x8;
typedef __attribute__((ext_vector_type(8))) unsigned short u16x8;
typedef __attribute__((ext_vector_type(4))) float f32x4;

__device__ __forceinline__ float lrelu(float v) { return v > 0.f ? v : 0.2f * v; }

__device__ __forceinline__ unsigned short f2bf(float f) {   // RNE
  unsigned u = __float_as_uint(f);
  u += 0x7fffu + ((u >> 16) & 1u);
  return (unsigned short)(u >> 16);
}
__device__ __forceinline__ float bf2f(unsigned short u) {
  return __uint_as_float((unsigned)u << 16);
}

// ---- attn row fill: zero 32KB row (NT) + set edge positions; needs src-CSR only ----
__device__ __forceinline__ void attn_fill_row(int row, const int* __restrict__ csrdst,
    const int* __restrict__ rowst_s, float* __restrict__ attn) {
  float* rp = attn + (size_t)row * NNODES;
  f32x4* p4 = (f32x4*)rp;
  f32x4 z = {0.f, 0.f, 0.f, 0.f};
#pragma unroll
  for (int j = 0; j < 8; ++j)
    __builtin_nontemporal_store(z, p4 + j * 256 + threadIdx.x);
  __syncthreads();
  int e0 = rowst_s[row], e1 = rowst_s[row + 1];
  for (int j = e0 + (int)threadIdx.x; j < e1; j += 256)
    rp[csrdst[j]] = 16384.0f / 270336.0f;
}

// ---------------- merged weight pre-transpose (RNE bf16) + zero-init ----------------
__device__ __forceinline__ void wsplit_body(const float* __restrict__ W,
    unsigned short* __restrict__ Th, int K, int blk) {
  int col = threadIdx.x;
  int kb = blk * 8;
  u16x8 vh;
#pragma unroll
  for (int i = 0; i < 8; ++i)
    vh[i] = f2bf(W[(size_t)(kb + i) * 256 + col]);
  *(u16x8*)(Th + (size_t)col * K + kb) = vh;
}

__global__ __launch_bounds__(256) void k_wsplit_all(
    const float* __restrict__ Wd, const float* __restrict__ Wc, const float* __restrict__ Wg,
    const float* __restrict__ W1l, const float* __restrict__ W1r,
    const float* __restrict__ W2l, const float* __restrict__ W2r,
    unsigned short* __restrict__ tdh, unsigned short* __restrict__ tch,
    unsigned short* __restrict__ tgh,
    unsigned short* __restrict__ tl1h, unsigned short* __restrict__ tr1h,
    unsigned short* __restrict__ tl2h, unsigned short* __restrict__ tr2h,
    int* __restrict__ counts_d, int* __restrict__ counts_s, float* __restrict__ stats) {
  int b = blockIdx.x;
  if      (b < 256)  wsplit_body(Wd,  tdh, 2048, b);
  else if (b < 512)  wsplit_body(Wc,  tch, 2048, b - 256);
  else if (b < 1024) wsplit_body(Wg,  tgh, 4096, b - 512);
  else if (b < 1056) { wsplit_body(W1l, tl1h, 256, b - 1024);
                       counts_d[(b - 1024) * 256 + threadIdx.x] = 0; }
  else if (b < 1088) { wsplit_body(W1r, tr1h, 256, b - 1056);
                       counts_s[(b - 1056) * 256 + threadIdx.x] = 0; }
  else if (b < 1120) { wsplit_body(W2l, tl2h, 256, b - 1088);
                       if (b < 1092) stats[(b - 1088) * 256 + threadIdx.x] = 0.f; }
  else               wsplit_body(W2r, tr2h, 256, b - 1120);
}

// ---------------- 128x128 MFMA 1-term bf16 GEMM tile, 2-deep reg pipeline ----------
// ABF: A operand already bf16 (direct LDS copy unless NORM rescales it).
struct Tile128 {
  unsigned short Ah[128][40], Bh[128][40];   // +8 pad: bank spread (20 KB)
};
struct TileN {       // NORM variant carries per-channel scale/shift in LDS
  Tile128 t;
  float nsc[256], nsh[256];
};

template<bool BIAS, bool OUTBF, bool NORM, bool ABF>
__device__ __forceinline__ void gemm_tile128(Tile128& s,
    const void* __restrict__ Av, int lda,
    const unsigned short* __restrict__ Th, int ldb, int nsteps,
    const float* __restrict__ bias, float* __restrict__ C,
    unsigned short* __restrict__ Cb,
    const float* __restrict__ nsc, const float* __restrict__ nsh) {
  const int tid = threadIdx.x;
  const int wave = tid >> 6, lane = tid & 63;
  const int g = lane >> 4, r = lane & 15;
  const int wr = (wave >> 1) * 64, wc = (wave & 1) * 64;

  const int ar = tid >> 1, ak = (tid & 1) * 16;      // A: 128 rows x 32 k
  const float* ArowF = (const float*)Av + (size_t)ar * lda + ak;
  const unsigned short* ArowB = (const unsigned short*)Av + (size_t)ar * lda + ak;
  const int bc = tid & 127, bk = (tid >> 7) * 16;    // B: 128 cols x 32 k
  const unsigned short* Bhs = Th + (size_t)bc * ldb + bk;

  f32x4 acc[4][4];
#pragma unroll
  for (int m = 0; m < 4; ++m)
#pragma unroll
    for (int n = 0; n < 4; ++n)
#pragma unroll
      for (int j = 0; j < 4; ++j) acc[m][n][j] = 0.f;

  // 2-deep register pipeline: q* = step t (to stage), p* = step t+1 (in flight)
  float4 qa0, qa1, qa2, qa3, pa0, pa1, pa2, pa3;
  u16x8 qA0, qA1, pA0, pA1;
  if constexpr (ABF) {
    qA0 = *(const u16x8*)(ArowB);
    qA1 = *(const u16x8*)(ArowB + 8);
  } else {
    qa0 = *(const float4*)(ArowF);
    qa1 = *(const float4*)(ArowF + 4);
    qa2 = *(const float4*)(ArowF + 8);
    qa3 = *(const float4*)(ArowF + 12);
  }
  u16x8 qb0 = *(const u16x8*)(Bhs);
  u16x8 qb1 = *(const u16x8*)(Bhs + 8);
  u16x8 pb0, pb1;
  if (nsteps > 1) {
    if constexpr (ABF) {
      pA0 = *(const u16x8*)(ArowB + 32);
      pA1 = *(const u16x8*)(ArowB + 40);
    } else {
      pa0 = *(const float4*)(ArowF + 32);
      pa1 = *(const float4*)(ArowF + 36);
      pa2 = *(const float4*)(ArowF + 40);
      pa3 = *(const float4*)(ArowF + 44);
    }
    pb0 = *(const u16x8*)(Bhs + 32);
    pb1 = *(const u16x8*)(Bhs + 40);
  }

  for (int t = 0; t < nsteps; ++t) {
    if constexpr (ABF) {
      if constexpr (NORM) {
        u16x8 vh0, vh1;
#pragma unroll
        for (int i = 0; i < 8; ++i) {
          int ch = t * 32 + ak + i;
          float v = fmaxf(bf2f(qA0[i]) * nsc[ch] + nsh[ch], 0.f);
          vh0[i] = f2bf(v);
          int ch2 = ch + 8;
          float v2 = fmaxf(bf2f(qA1[i]) * nsc[ch2] + nsh[ch2], 0.f);
          vh1[i] = f2bf(v2);
        }
        *(u16x8*)&s.Ah[ar][ak]     = vh0;
        *(u16x8*)&s.Ah[ar][ak + 8] = vh1;
      } else {
        *(u16x8*)&s.Ah[ar][ak]     = qA0;
        *(u16x8*)&s.Ah[ar][ak + 8] = qA1;
      }
    } else {
      float av[16] = {qa0.x, qa0.y, qa0.z, qa0.w, qa1.x, qa1.y, qa1.z, qa1.w,
                      qa2.x, qa2.y, qa2.z, qa2.w, qa3.x, qa3.y, qa3.z, qa3.w};
      u16x8 vh0, vh1;
#pragma unroll
      for (int i = 0; i < 16; ++i) {
        unsigned short hh = f2bf(av[i]);
        if (i < 8) vh0[i] = hh;
        else       vh1[i - 8] = hh;
      }
      *(u16x8*)&s.Ah[ar][ak]     = vh0;
      *(u16x8*)&s.Ah[ar][ak + 8] = vh1;
    }
    *(u16x8*)&s.Bh[bc][bk]     = qb0;
    *(u16x8*)&s.Bh[bc][bk + 8] = qb1;
    __syncthreads();
    // rotate pipeline and issue step t+2's loads (2 compute-phases of cover)
    if constexpr (ABF) { qA0 = pA0; qA1 = pA1; }
    else { qa0 = pa0; qa1 = pa1; qa2 = pa2; qa3 = pa3; }
    qb0 = pb0; qb1 = pb1;
    if (t + 2 < nsteps) {
      if constexpr (ABF) {
        const unsigned short* An = ArowB + (size_t)(t + 2) * 32;
        pA0 = *(const u16x8*)(An);
        pA1 = *(const u16x8*)(An + 8);
      } else {
        const float* An = ArowF + (size_t)(t + 2) * 32;
        pa0 = *(const float4*)(An);
        pa1 = *(const float4*)(An + 4);
        pa2 = *(const float4*)(An + 8);
        pa3 = *(const float4*)(An + 12);
      }
      const unsigned short* Bhn = Bhs + (size_t)(t + 2) * 32;
      pb0 = *(const u16x8*)(Bhn);
      pb1 = *(const u16x8*)(Bhn + 8);
    }
    s16x8 fah[4], fbh[4];
#pragma unroll
    for (int m = 0; m < 4; ++m)
      fah[m] = *(const s16x8*)&s.Ah[wr + m * 16 + r][g * 8];
#pragma unroll
    for (int n = 0; n < 4; ++n)
      fbh[n] = *(const s16x8*)&s.Bh[wc + n * 16 + r][g * 8];
#pragma unroll
    for (int m = 0; m < 4; ++m)
#pragma unroll
      for (int n = 0; n < 4; ++n)
        acc[m][n] = __builtin_amdgcn_mfma_f32_16x16x32_bf16(fah[m], fbh[n], acc[m][n], 0, 0, 0);
    __syncthreads();
  }
  // epilogue: C/D layout col=lane&15, row=(lane>>4)*4+reg [m89]
#pragma unroll
  for (int m = 0; m < 4; ++m)
#pragma unroll
    for (int n = 0; n < 4; ++n) {
      int col = wc + n * 16 + r;
      float bv = BIAS ? bias[col] : 0.f;
      int rowb = wr + m * 16 + g * 4;
#pragma unroll
      for (int j = 0; j < 4; ++j) {
        float v = acc[m][n][j] + bv;
        if constexpr (OUTBF) Cb[(size_t)(rowb + j) * 256 + col] = f2bf(v);
        else                 C[(size_t)(rowb + j) * 256 + col] = v;
      }
    }
}

// ---- merged: split-K input projections (blocks 0..511) + attn fill rows 0..4095 ----
// Partials written as bf16 (halves Ppart round-trip traffic).
#define PDRUG_PLANE ((size_t)2048 * 256)
#define PGENE_PLANE ((size_t)4096 * 256)
__global__ __launch_bounds__(256) void k_inproj_fill(
    const float* __restrict__ drug, const float* __restrict__ cell,
    const float* __restrict__ gene,
    const unsigned short* __restrict__ tdh, const unsigned short* __restrict__ tch,
    const unsigned short* __restrict__ tgh, unsigned short* __restrict__ P,
    const int* __restrict__ csrdst, const int* __restrict__ rowst_s,
    float* __restrict__ attn) {
  __shared__ Tile128 s;
  int b = blockIdx.x;
  if (b >= 512) { attn_fill_row(b - 512, csrdst, rowst_s, attn); return; }
  if (b < 256) {          // drug (b<128) / cell: 16 rowblk x 2 colblk x 4 kchunk (K=512)
    int idx = b & 127;
    int colblk = (idx >> 3) & 1;
    int rest = (idx & 7) | ((idx >> 4) << 3);   // 0..63
    int rowblk = rest >> 2, chunk = rest & 3;
    const float* X = (b < 128) ? drug : cell;
    const unsigned short* Th = (b < 128) ? tdh : tch;
    unsigned short* Pb = P + ((b < 128) ? 0 : 4 * PDRUG_PLANE);
    gemm_tile128<false, true, false, false>(s,
        X + (size_t)rowblk * 128 * 2048 + (size_t)chunk * 512, 2048,
        Th + (size_t)colblk * 128 * 2048 + chunk * 512, 2048, 16, nullptr, nullptr,
        Pb + (size_t)chunk * PDRUG_PLANE + (size_t)rowblk * 128 * 256 + colblk * 128,
        nullptr, nullptr);
  } else {                // gene: 32 rowblk x 2 colblk x 4 kchunk (K=1024, 32 steps)
    int idx = b - 256;    // 0..255
    int colblk = (idx >> 3) & 1;
    int rest = (idx & 7) | ((idx >> 4) << 3);   // 0..127
    int rowblk = rest >> 2, chunk = rest & 3;
    gemm_tile128<false, true, false, false>(s,
        gene + (size_t)rowblk * 128 * 4096 + (size_t)chunk * 1024, 4096,
        tgh + (size_t)colblk * 128 * 4096 + chunk * 1024, 4096, 32, nullptr, nullptr,
        P + 8 * PDRUG_PLANE + (size_t)chunk * PGENE_PLANE + (size_t)rowblk * 128 * 256 + colblk * 128,
        nullptr, nullptr);
  }
}

// reduce bf16 partial planes (np=4 uniform) + bias -> bufAb [8192, 256] bf16
__global__ __launch_bounds__(256) void k_reduce(const unsigned short* __restrict__ P,
    const float* __restrict__ bd, const float* __restrict__ bc,
    const float* __restrict__ bg, unsigned short* __restrict__ out) {
  int idx = blockIdx.x * 256 + threadIdx.x;   // ushort4 index
  size_t e = (size_t)idx * 4;
  int row = (int)(e >> 8);
  int col = (int)(e & 255);
  const unsigned short* base; const float* bias; size_t plane;
  if (row < 2048) {
    base = P + (size_t)row * 256 + col; bias = bd; plane = PDRUG_PLANE;
  } else if (row < 4096) {
    base = P + 4 * PDRUG_PLANE + (size_t)(row - 2048) * 256 + col; bias = bc;
    plane = PDRUG_PLANE;
  } else {
    base = P + 8 * PDRUG_PLANE + (size_t)(row - 4096) * 256 + col; bias = bg;
    plane = PGENE_PLANE;
  }
  float sx = 0.f, sy = 0.f, sz = 0.f, sw = 0.f;
#pragma unroll
  for (int p = 0; p < 4; ++p) {
    ushort4 v = *(const ushort4*)(base + p * plane);
    sx += bf2f(v.x); sy += bf2f(v.y); sz += bf2f(v.z); sw += bf2f(v.w);
  }
  float4 bv = *(const float4*)(bias + col);
  ushort4 r;
  r.x = f2bf(sx + bv.x); r.y = f2bf(sy + bv.y);
  r.z = f2bf(sz + bv.z); r.w = f2bf(sw + bv.w);
  *(ushort4*)(out + e) = r;
}

// merged layer GEMMs (blocks 0..255) + attn fill backfill (blocks 256..1279).
template<bool NORM>
__global__ __launch_bounds__(256) void k_gemm2(const unsigned short* __restrict__ A,
    const unsigned short* __restrict__ ThL, const unsigned short* __restrict__ ThR,
    const float* __restrict__ biasL, const float* __restrict__ biasR,
    unsigned short* __restrict__ CLb, unsigned short* __restrict__ CRb,
    const float* __restrict__ csum, const float* __restrict__ csumsq,
    const float* __restrict__ gamma, const float* __restrict__ beta,
    const float* __restrict__ mscale,
    const int* __restrict__ csrdst, const int* __restrict__ rowst_s,
    float* __restrict__ attn, int fill_base) {
  __shared__ TileN s;
  int b = blockIdx.x;
  if (b >= 256) { attn_fill_row(fill_base + b - 256, csrdst, rowst_s, attn); return; }
  int sub = (b >> 3) & 3;
  int x = (b & 7) | ((b >> 5) << 3);     // 0..63
  if constexpr (NORM) {
    int c = threadIdx.x;
    float mu = csum[c] * (1.0f / 8192.0f);
    float ex2 = csumsq[c] * (1.0f / 8192.0f);
    float smu = mscale[c] * mu;
    float var = ex2 - 2.f * smu * mu + smu * smu;
    float sc = rsqrtf(var + 1e-5f) * gamma[c];
    s.nsc[c] = sc;
    s.nsh[c] = beta[c] - smu * sc;
    __syncthreads();
  }
  int row0 = x * 128;
  int col0 = (sub & 1) * 128;
  if (sub >= 2) {
    gemm_tile128<true, true, NORM, true>(s.t, A + (size_t)row0 * 256, 256,
        ThR + (size_t)col0 * 256, 256, 8,
        biasR + col0, nullptr, CRb + (size_t)row0 * 256 + col0, s.nsc, s.nsh);
  } else {
    gemm_tile128<true, true, NORM, true>(s.t, A + (size_t)row0 * 256, 256,
        ThL + (size_t)col0 * 256, 256, 8,
        biasL + col0, nullptr, CLb + (size_t)row0 * 256 + col0, s.nsc, s.nsh);
  }
}

// ---------------- dual CSR build (counting sort by dst AND by src) ----------------
__global__ void k_count2(const int* __restrict__ edges, int* __restrict__ cd,
                         int* __restrict__ cs) {
  int e = blockIdx.x * blockDim.x + threadIdx.x;
  if (e >= EETOT) return;
  int s, d;
  if (e < NEDGE) { s = edges[e]; d = edges[NEDGE + e]; } else { s = d = e - NEDGE; }
  atomicAdd(&cd[d], 1);
  atomicAdd(&cs[s], 1);
}

__global__ __launch_bounds__(1024) void k_scan2(
    const int* __restrict__ c0, int* __restrict__ r0, int* __restrict__ u0,
    const int* __restrict__ c1, int* __restrict__ r1, int* __restrict__ u1) {
  const int* counts = blockIdx.x ? c1 : c0;
  int* row_start = blockIdx.x ? r1 : r0;
  int* cursor = blockIdx.x ? u1 : u0;
  __shared__ int part[1024];
  int t = threadIdx.x;
  int base = t * 8;
  int loc[8];
  int s = 0;
#pragma unroll
  for (int j = 0; j < 8; ++j) { loc[j] = s; s += counts[base + j]; }
  part[t] = s;
  __syncthreads();
  for (int off = 1; off < 1024; off <<= 1) {
    int v = (t >= off) ? part[t - off] : 0;
    __syncthreads();
    part[t] += v;
    __syncthreads();
  }
  int pre = (t == 0) ? 0 : part[t - 1];
#pragma unroll
  for (int j = 0; j < 8; ++j) {
    int v = pre + loc[j];
    row_start[base + j] = v;
    cursor[base + j] = v;
  }
  if (t == 1023) row_start[NNODES] = pre + s;
}

__global__ void k_place2(const int* __restrict__ edges, int* __restrict__ curd,
    int* __restrict__ curs, int* __restrict__ csrsrc, int* __restrict__ csrdst) {
  int e = blockIdx.x * blockDim.x + threadIdx.x;
  if (e >= EETOT) return;
  int s, d;
  if (e < NEDGE) { s = edges[e]; d = edges[NEDGE + e]; } else { s = d = e - NEDGE; }
  int pd = atomicAdd(&curd[d], 1);
  csrsrc[pd] = s;                       // src ids ordered by dst (for k_gat)
  int ps = atomicAdd(&curs[s], 1);
  csrdst[ps] = d;                       // dst ids ordered by src (for attnfill)
}

// ---- fused GAT edge phase (blocks 0..2047) + attn fill backfill (2048..3071) ----
__global__ __launch_bounds__(256) void k_gat(
    const unsigned short* __restrict__ xl, const unsigned short* __restrict__ xr,
    const float* __restrict__ att, const int* __restrict__ csrsrc,
    const int* __restrict__ row_start, const float* __restrict__ bias,
    unsigned short* __restrict__ out,
    const int* __restrict__ csrdst, const int* __restrict__ rowst_s,
    float* __restrict__ attn, int fill_base) {
  if (blockIdx.x >= 2048) {
    attn_fill_row(fill_base + blockIdx.x - 2048, csrdst, rowst_s, attn);
    return;
  }
  int i = blockIdx.x * 4 + (threadIdx.x >> 6);
  int lane = threadIdx.x & 63;
  int co = (lane >> 4) * 64 + (lane & 15) * 4;   // head*64 + channel
  float4 w4 = *(const float4*)(att + co);
  ushort4 ur = *(const ushort4*)(xr + (size_t)i * 256 + co);
  float4 r4;
  r4.x = bf2f(ur.x); r4.y = bf2f(ur.y); r4.z = bf2f(ur.z); r4.w = bf2f(ur.w);
  float sum = 0.f, ax = 0.f, ay = 0.f, az = 0.f, aw = 0.f;
  int e0 = row_start[i], e1 = row_start[i + 1];   // >=1 edge (self loop)
  int deg = e1 - e0;

  for (int cb = 0; cb < deg; cb += 64) {          // chunks of <=64 edges
    int cn = min(deg - cb, 64);                   // wave-uniform
    int myid = (lane < cn) ? csrsrc[e0 + cb + lane] : 0;
    auto g = [&](int j) {
      int s = __shfl(myid, j);
      return *(const ushort4*)(xl + (size_t)s * 256 + co);
    };
    ushort4 cur[8], nxt[8];
    int curn = min(cn, 8);
#pragma unroll
    for (int j = 0; j < 8; ++j)
      if (j < curn) cur[j] = g(j);
    int p = curn;
    for (;;) {
      int nxtn = min(cn - p, 8);                  // wave-uniform
#pragma unroll
      for (int j = 0; j < 8; ++j)
        if (j < nxtn) nxt[j] = g(p + j);
#pragma unroll
      for (int j = 0; j < 8; ++j) {
        if (j >= curn) break;
        ushort4 u = cur[j];
        float x0 = bf2f(u.x), x1 = bf2f(u.y), x2 = bf2f(u.z), x3 = bf2f(u.w);
        float t = w4.x * lrelu(x0 + r4.x) + w4.y * lrelu(x1 + r4.y) +
                  w4.z * lrelu(x2 + r4.z) + w4.w * lrelu(x3 + r4.w);
        t += __shfl_xor(t, 1);
        t += __shfl_xor(t, 2);
        t += __shfl_xor(t, 4);
        t += __shfl_xor(t, 8);
        float el = __expf(fminf(t, 60.f));
        sum += el;
        ax += el * x0; ay += el * x1; az += el * x2; aw += el * x3;
      }
      if (nxtn <= 0) break;
#pragma unroll
      for (int j = 0; j < 8; ++j) cur[j] = nxt[j];
      curn = nxtn; p += nxtn;
    }
  }
  float inv = 1.0f / sum;
  float4 bv = *(const float4*)(bias + co);
  ushort4 r;
  r.x = f2bf(ax * inv + bv.x); r.y = f2bf(ay * inv + bv.y);
  r.z = f2bf(az * inv + bv.z); r.w = f2bf(aw * inv + bv.w);
  *(ushort4*)(out + (size_t)i * 256 + co) = r;
}

// ---------------- GraphNorm stats (col sum / sumsq), bf16 input ----------------
__global__ __launch_bounds__(256) void k_colstats(const unsigned short* __restrict__ x,
    float* __restrict__ csum, float* __restrict__ csumsq) {
  int c = threadIdx.x;
  int r0 = blockIdx.x * 32;
  float s = 0.f, s2 = 0.f;
  for (int r = 0; r < 32; ++r) {
    float v = bf2f(x[(size_t)(r0 + r) * 256 + c]);
    s += v; s2 += v * v;
  }
  atomicAdd(&csum[c], s);
  atomicAdd(&csumsq[c], s2);
}

// ---------------- pair head with fused GraphNorm+ReLU of the final features -------
__global__ __launch_bounds__(256) void k_pred(const unsigned short* __restrict__ h,
    const int* __restrict__ idx_drug, const int* __restrict__ idx_cell,
    const float* __restrict__ W, const float* __restrict__ b,
    const float* __restrict__ csum, const float* __restrict__ csumsq,
    const float* __restrict__ gamma, const float* __restrict__ beta,
    const float* __restrict__ mscale, float* __restrict__ out) {
  int p = blockIdx.x * 4 + (threadIdx.x >> 6);
  if (p >= NPAIRS) return;
  int lane = threadIdx.x & 63;
  int rd = idx_drug[p], rc = idx_cell[p];
  ushort4 a  = *(const ushort4*)(h + (size_t)rd * 256 + lane * 4);
  ushort4 cg = *(const ushort4*)(h + (size_t)rc * 256 + lane * 4);
  float4 wa = *(const float4*)(W + lane * 4);
  float4 wc = *(const float4*)(W + 256 + lane * 4);
  float av[4] = {bf2f(a.x), bf2f(a.y), bf2f(a.z), bf2f(a.w)};
  float cv[4] = {bf2f(cg.x), bf2f(cg.y), bf2f(cg.z), bf2f(cg.w)};
  float wv[4] = {wa.x, wa.y, wa.z, wa.w};
  float uv[4] = {wc.x, wc.y, wc.z, wc.w};
  float t = 0.f;
#pragma unroll
  for (int j = 0; j < 4; ++j) {
    int ch = lane * 4 + j;
    float mu = csum[ch] * (1.0f / 8192.0f);
    float ex2 = csumsq[ch] * (1.0f / 8192.0f);
    float smu = mscale[ch] * mu;
    float var = ex2 - 2.f * smu * mu + smu * smu;
    float sc = rsqrtf(var + 1e-5f) * gamma[ch];
    float sh = beta[ch] - smu * sc;
    t += fmaxf(av[j] * sc + sh, 0.f) * wv[j] + fmaxf(cv[j] * sc + sh, 0.f) * uv[j];
  }
#pragma unroll
  for (int off = 1; off < 64; off <<= 1) t += __shfl_xor(t, off);
  if (lane == 0) out[p] = 1.0f / (1.0f + __expf(-(t + b[0])));
}

extern "C" void kernel_launch(void* const* d_in, const int* in_sizes, int n_in,
                              void* d_out, int out_size, void* d_ws, size_t ws_size,
                              hipStream_t stream) {
  const float* drug = (const float*)d_in[0];
  const float* cell = (const float*)d_in[1];
  const float* gene = (const float*)d_in[2];
  const int*   edges = (const int*)d_in[3];
  const int*   idxd = (const int*)d_in[4];
  const int*   idxc = (const int*)d_in[5];
  const float* Wd = (const float*)d_in[6];   const float* bd = (const float*)d_in[7];
  const float* Wc = (const float*)d_in[8];   const float* bc = (const float*)d_in[9];
  const float* Wg = (const float*)d_in[10];  const float* bg = (const float*)d_in[11];
  const float* g1Wl = (const float*)d_in[12]; const float* g1bl = (const float*)d_in[13];
  const float* g1Wr = (const float*)d_in[14]; const float* g1br = (const float*)d_in[15];
  const float* g1att = (const float*)d_in[16]; const float* g1bias = (const float*)d_in[17];
  const float* g2Wl = (const float*)d_in[18]; const float* g2bl = (const float*)d_in[19];
  const float* g2Wr = (const float*)d_in[20]; const float* g2br = (const float*)d_in[21];
  const float* g2att = (const float*)d_in[22]; const float* g2bias = (const float*)d_in[23];
  const float* gn1g = (const float*)d_in[24]; const float* gn1b = (const float*)d_in[25];
  const float* gn1s = (const float*)d_in[26];
  const float* gn2g = (const float*)d_in[27]; const float* gn2b = (const float*)d_in[28];
  const float* gn2s = (const float*)d_in[29];
  const float* linW = (const float*)d_in[30]; const float* linb = (const float*)d_in[31];
  float* out = (float*)d_out;
  (void)in_sizes; (void)n_in; (void)out_size; (void)ws_size;

  char* ws = (char*)d_ws;
  size_t off = 0;
  auto take = [&](size_t bytes) -> void* {
    void* p = ws + off;
    off += (bytes + 255) & ~(size_t)255;
    return p;
  };
  unsigned short* bufAb = (unsigned short*)take((size_t)NNODES * 256 * 2);  // features bf16
  unsigned short* bufBb = (unsigned short*)take((size_t)NNODES * 256 * 2);  // xl bf16
  unsigned short* bufCb = (unsigned short*)take((size_t)NNODES * 256 * 2);  // xr bf16
  int* counts_d = (int*)take((size_t)NNODES * 4);
  int* counts_s = (int*)take((size_t)NNODES * 4);
  float* stats  = (float*)take(4 * 256 * 4);     // csum0|csumsq0|csum1|csumsq1
  int* rowst_d  = (int*)take((size_t)(NNODES + 1) * 4);
  int* rowst_s  = (int*)take((size_t)(NNODES + 1) * 4);
  int* cursor_d = (int*)take((size_t)NNODES * 4);
  int* cursor_s = (int*)take((size_t)NNODES * 4);
  int* csrsrc   = (int*)take((size_t)EETOT * 4);
  int* csrdst   = (int*)take((size_t)EETOT * 4);
  unsigned short* tdh = (unsigned short*)take((size_t)256 * 2048 * 2);
  unsigned short* tch = (unsigned short*)take((size_t)256 * 2048 * 2);
  unsigned short* tgh = (unsigned short*)take((size_t)256 * 4096 * 2);
  unsigned short* tl1h = (unsigned short*)take((size_t)256 * 256 * 2);
  unsigned short* tr1h = (unsigned short*)take((size_t)256 * 256 * 2);
  unsigned short* tl2h = (unsigned short*)take((size_t)256 * 256 * 2);
  unsigned short* tr2h = (unsigned short*)take((size_t)256 * 256 * 2);
  unsigned short* Ppart = (unsigned short*)take((8 * PDRUG_PLANE + 4 * PGENE_PLANE) * 2);
  float* attn = out + NPAIRS;

  // ---- weight transpose (bf16 RNE) + zero-init of counts & stats (one kernel) ----
  k_wsplit_all<<<1152, 256, 0, stream>>>(Wd, Wc, Wg, g1Wl, g1Wr, g2Wl, g2Wr,
      tdh, tch, tgh, tl1h, tr1h, tl2h, tr2h, counts_d, counts_s, stats);

  // ---- dual CSR build ----
  k_count2<<<EETOT / 256, 256, 0, stream>>>(edges, counts_d, counts_s);
  k_scan2<<<2, 1024, 0, stream>>>(counts_d, rowst_d, cursor_d, counts_s, rowst_s, cursor_s);
  k_place2<<<EETOT / 256, 256, 0, stream>>>(edges, cursor_d, cursor_s, csrsrc, csrdst);

  // ---- input projections + attn fill rows 0..4095 ----
  k_inproj_fill<<<512 + 4096, 256, 0, stream>>>(drug, cell, gene, tdh, tch, tgh,
      Ppart, csrdst, rowst_s, attn);
  k_reduce<<<NNODES * 256 / 4 / 256, 256, 0, stream>>>(Ppart, bd, bc, bg, bufAb);

  // ---- layer 0 (raw A); fill rows 4096..5119 / 5120..6143 backfilled ----
  k_gemm2<false><<<256 + 1024, 256, 0, stream>>>(bufAb, tl1h, tr1h, g1bl, g1br,
      bufBb, bufCb, nullptr, nullptr, nullptr, nullptr, nullptr,
      csrdst, rowst_s, attn, 4096);
  k_gat<<<2048 + 1024, 256, 0, stream>>>(bufBb, bufCb, g1att, csrsrc, rowst_d, g1bias,
      bufAb, csrdst, rowst_s, attn, 5120);
  k_colstats<<<NNODES / 32, 256, 0, stream>>>(bufAb, stats, stats + 256);

  // ---- layer 1 (GraphNorm+ReLU fused into A-staging); fill rows 6144..8191 ----
  k_gemm2<true><<<256 + 1024, 256, 0, stream>>>(bufAb, tl2h, tr2h, g2bl, g2br,
      bufBb, bufCb, stats, stats + 256, gn1g, gn1b, gn1s,
      csrdst, rowst_s, attn, 6144);
  k_gat<<<2048 + 1024, 256, 0, stream>>>(bufBb, bufCb, g2att, csrsrc, rowst_d, g2bias,
      bufAb, csrdst, rowst_s, attn, 7168);
  k_colstats<<<NNODES / 32, 256, 0, stream>>>(bufAb, stats + 512, stats + 768);

  // ---- pair predictions (final GraphNorm+ReLU fused) -> out[0..9999] ----
  k_pred<<<NPAIRS / 4, 256, 0, stream>>>(bufAb, idxd, idxc, linW, linb,
      stats + 512, stats + 768, gn2g, gn2b, gn2s, out);
}